// Round 4
// baseline (473.701 us; speedup 1.0000x reference)
//
#include <hip/hip_runtime.h>

// Problem constants (fixed by the reference): B=4, S=2048, D=DK=1024.
constexpr int Bc  = 4;
constexpr int Sc  = 2048;
constexpr int Dc  = 1024;
constexpr int DKc = 1024;
constexpr long BSc = (long)Bc * Sc;      // 8192 flattened rows of x

typedef __attribute__((ext_vector_type(8))) __bf16 bf16x8;
typedef __attribute__((ext_vector_type(4))) float  floatx4;

__device__ inline __bf16 f2bf(float f) {
  unsigned u = __builtin_bit_cast(unsigned, f);
  u = (u + 0x7FFFu + ((u >> 16) & 1u)) >> 16;      // RNE
  unsigned short s = (unsigned short)u;
  return __builtin_bit_cast(__bf16, s);
}
__device__ inline float bf2f(__bf16 h) {
  unsigned u = ((unsigned)__builtin_bit_cast(unsigned short, h)) << 16;
  return __builtin_bit_cast(float, u);
}

// async global->LDS, 16B per lane. lds base must be wave-uniform; HW scatters
// lane i's 16B to ldsbase + i*16.
__device__ inline void stage16(const __bf16* g, __bf16* l) {
  __builtin_amdgcn_global_load_lds(
      (const __attribute__((address_space(1))) unsigned int*)g,
      (__attribute__((address_space(3))) unsigned int*)l, 16, 0, 0);
}

// ---------------------------------------------------------------------------
// fp32 -> hi + lo bf16 split, element-wise (used for x, WQ, WK).
// ---------------------------------------------------------------------------
__global__ __launch_bounds__(256) void cast_split(const float* __restrict__ in,
                                                  __bf16* __restrict__ hi,
                                                  __bf16* __restrict__ lo) {
  long i = (long)blockIdx.x * 256 + threadIdx.x;
  float f = in[i];
  __bf16 h = f2bf(f);
  hi[i] = h;
  lo[i] = f2bf(f - bf2f(h));
}

// ---------------------------------------------------------------------------
// W [D][DK] fp32 -> Wt hi/lo [DK][D] bf16 (transposed split). For WV only.
// ---------------------------------------------------------------------------
__global__ __launch_bounds__(256) void transpose_split(const float* __restrict__ in,
                                                       __bf16* __restrict__ hi,
                                                       __bf16* __restrict__ lo) {
  __shared__ float tile[32][33];
  int xI = blockIdx.x * 32 + threadIdx.x;
  int yI = blockIdx.y * 32 + threadIdx.y;
#pragma unroll
  for (int j = 0; j < 32; j += 8)
    tile[threadIdx.y + j][threadIdx.x] = in[(long)(yI + j) * DKc + xI];
  __syncthreads();
  int xO = blockIdx.y * 32 + threadIdx.x;
  int yO = blockIdx.x * 32 + threadIdx.y;
#pragma unroll
  for (int j = 0; j < 32; j += 8) {
    float v = tile[threadIdx.x][threadIdx.y + j];
    long idx = (long)(yO + j) * Dc + xO;
    __bf16 h = f2bf(v);
    hi[idx] = h;
    lo[idx] = f2bf(v - bf2f(h));
  }
}

// ---------------------------------------------------------------------------
// m97-structure NT MFMA GEMM: C[M][N] = A[M][K] * Bt[N][K]^T, row-major bf16.
// 128x128 block tile, 4 waves 2x2, each 64x64 (4x4 accs of 16x16x32).
// BK=32 staged via global_load_lds width=16; XOR-swizzled on the global
// source side (round-3: conflicts 8.4M -> 0).
//
// MODE_QK: split (3 MFMA), bf16 hi+lo store via LDS round-trip (coalesced).
//          Used for G = WK*WQ^T (M=N=K=1024) and T = x*Gt (M=8192).
// MODE_V : plain, TRANSPOSED store via LDS -> Vt[b][n][seq]
// MODE_S : split, fp32 store * scale, z=B              (M=2048,N=2048,K=1024)
// MODE_PV: plain, fp32 store, z=B                      (M=2048,N=1024,K=2048)
// ---------------------------------------------------------------------------
enum { MODE_QK = 0, MODE_V = 1, MODE_S = 2, MODE_PV = 3 };

template <int MODE>
__global__ __launch_bounds__(256) void gemm_tile(
    const __bf16* __restrict__ Ahi, const __bf16* __restrict__ Alo,
    const __bf16* __restrict__ Bhi, const __bf16* __restrict__ Blo,
    float* __restrict__ Cf, __bf16* __restrict__ Chi, __bf16* __restrict__ Clo,
    float scale) {
  constexpr bool SPLIT = (MODE == MODE_QK || MODE == MODE_S);
  constexpr int  K = (MODE == MODE_PV) ? Sc : Dc;
  constexpr int  N = (MODE == MODE_S) ? Sc : DKc;
  constexpr long aBatch = (MODE == MODE_S) ? (long)Sc * DKc
                        : (MODE == MODE_PV) ? (long)Sc * Sc : 0;
  constexpr long bBatch = (MODE == MODE_S) ? (long)Sc * DKc
                        : (MODE == MODE_PV) ? (long)DKc * Sc : 0;
  constexpr long cBatch = (MODE == MODE_S) ? (long)Sc * Sc
                        : (MODE == MODE_PV) ? (long)Sc * DKc : 0;
  constexpr int SMEM = (SPLIT || MODE == MODE_V) ? 32768 : 16384;
  __shared__ __align__(16) char smem[SMEM];
  __bf16* sAh = (__bf16*)smem;           // [128][32] (chunk-swizzled)
  __bf16* sBh = sAh + 128 * 32;
  __bf16* sAl = sBh + 128 * 32;          // split only
  __bf16* sBl = sAl + 128 * 32;

  const int b    = blockIdx.z;
  const int wave = threadIdx.x >> 6;
  const int lane = threadIdx.x & 63;
  const int wm   = wave >> 1;            // 0..1
  const int wn   = wave & 1;             // 0..1
  const int m0   = blockIdx.y * 128;
  const int n0   = blockIdx.x * 128;

  const __bf16* Ab  = Ahi + (long)b * aBatch + (long)m0 * K;
  const __bf16* Bb  = Bhi + (long)b * bBatch + (long)n0 * K;
  const __bf16* Abl = SPLIT ? Alo + (long)b * aBatch + (long)m0 * K : nullptr;
  const __bf16* Bbl = SPLIT ? Blo + (long)b * bBatch + (long)n0 * K : nullptr;

  // Staging: wave w stages rows [w*32, w*32+32); lane (r,c) loads global
  // chunk c^((r>>1)&3) -> physical LDS slot base + lane*16B.
  const int sr   = lane >> 2;                       // 0..15
  const int sc_  = lane & 3;                        // 0..3
  const int scol = (sc_ ^ ((sr >> 1) & 3)) * 8;     // swizzled global col

  floatx4 acc[4][4];
  const floatx4 zero = {0.f, 0.f, 0.f, 0.f};
#pragma unroll
  for (int i = 0; i < 4; ++i)
#pragma unroll
    for (int j = 0; j < 4; ++j) acc[i][j] = zero;

  const int frow = lane & 15;
  // Fragment read: logical chunk = lane>>4; physical chunk is XOR'd by row.
  const int pko = ((lane >> 4) ^ ((frow >> 1) & 3)) * 8;

#pragma unroll 1
  for (int k0 = 0; k0 < K; k0 += 32) {
#pragma unroll
    for (int i = 0; i < 2; ++i) {
      const int rb = wave * 32 + i * 16;            // wave-uniform row base
      const long go = (long)(rb + sr) * K + k0 + scol;
      stage16(Ab + go, sAh + rb * 32);
      stage16(Bb + go, sBh + rb * 32);
      if constexpr (SPLIT) {
        stage16(Abl + go, sAl + rb * 32);
        stage16(Bbl + go, sBl + rb * 32);
      }
    }
    __syncthreads();

    bf16x8 af[4], bfr[4], afl[4], bfl[4];
#pragma unroll
    for (int t = 0; t < 4; ++t) {
      af[t]  = *(const bf16x8*)(sAh + (wm * 64 + t * 16 + frow) * 32 + pko);
      bfr[t] = *(const bf16x8*)(sBh + (wn * 64 + t * 16 + frow) * 32 + pko);
      if constexpr (SPLIT) {
        afl[t] = *(const bf16x8*)(sAl + (wm * 64 + t * 16 + frow) * 32 + pko);
        bfl[t] = *(const bf16x8*)(sBl + (wn * 64 + t * 16 + frow) * 32 + pko);
      }
    }
#pragma unroll
    for (int mt = 0; mt < 4; ++mt)
#pragma unroll
      for (int nt = 0; nt < 4; ++nt) {
        acc[mt][nt] = __builtin_amdgcn_mfma_f32_16x16x32_bf16(af[mt], bfr[nt], acc[mt][nt], 0, 0, 0);
        if constexpr (SPLIT) {
          acc[mt][nt] = __builtin_amdgcn_mfma_f32_16x16x32_bf16(af[mt], bfl[nt], acc[mt][nt], 0, 0, 0);
          acc[mt][nt] = __builtin_amdgcn_mfma_f32_16x16x32_bf16(afl[mt], bfr[nt], acc[mt][nt], 0, 0, 0);
        }
      }
    __syncthreads();
  }

  // Epilogue. D layout: col=lane&15, row=(lane>>4)*4+reg (m89/m91-verified).
  const int crow0 = (lane >> 4) * 4;
  const int ccol  = lane & 15;

  if constexpr (MODE == MODE_QK) {
    // bf16 hi/lo store via LDS round-trip: 2B scattered -> 16B coalesced.
    __bf16* sT = (__bf16*)smem;          // [128][128] bf16 = 32KB
#pragma unroll 1
    for (int pass = 0; pass < 2; ++pass) {
      __syncthreads();
#pragma unroll
      for (int nt = 0; nt < 4; ++nt) {
        int col = wn * 64 + nt * 16 + ccol;
#pragma unroll
        for (int mt = 0; mt < 4; ++mt) {
          int row = wm * 64 + mt * 16 + crow0;
#pragma unroll
          for (int r = 0; r < 4; ++r) {
            float v = acc[mt][nt][r] * scale;
            __bf16 h = f2bf(v);
            sT[(row + r) * 128 + col] = pass ? f2bf(v - bf2f(h)) : h;
          }
        }
      }
      __syncthreads();
      __bf16* dst = pass ? Clo : Chi;
#pragma unroll
      for (int c = 0; c < 8; ++c) {
        int flat = c * 2048 + threadIdx.x * 8;
        int row = flat >> 7, col = flat & 127;
        *(bf16x8*)(dst + (long)(m0 + row) * N + n0 + col) = *(const bf16x8*)(sT + flat);
      }
    }
    return;
  }

  if constexpr (MODE == MODE_V) {
    // Transpose through LDS (staging dead; reuse full 32KB as sT[128][128]).
    __bf16* sT = (__bf16*)smem;
#pragma unroll
    for (int nt = 0; nt < 4; ++nt) {
      int nl = wn * 64 + nt * 16 + ccol;
#pragma unroll
      for (int mt = 0; mt < 4; ++mt) {
        int ml = wm * 64 + mt * 16 + crow0;
#pragma unroll
        for (int r = 0; r < 4; ++r)
          sT[(long)nl * 128 + ml + r] = f2bf(acc[mt][nt][r]);
      }
    }
    __syncthreads();
    const int bb   = m0 >> 11;          // tile fully within one batch
    const int seq0 = m0 & (Sc - 1);
    __bf16* dst = Chi + (long)bb * DKc * Sc + seq0;
#pragma unroll
    for (int c = 0; c < 8; ++c) {
      int flat = c * 2048 + threadIdx.x * 8;   // elements; 16B per thread
      int row = flat >> 7, col = flat & 127;
      *(bf16x8*)(dst + (long)(n0 + row) * Sc + col) = *(const bf16x8*)(sT + flat);
    }
    return;
  }

#pragma unroll
  for (int nt = 0; nt < 4; ++nt) {
    int cn = n0 + wn * 64 + nt * 16 + ccol;
#pragma unroll
    for (int mt = 0; mt < 4; ++mt) {
#pragma unroll
      for (int r = 0; r < 4; ++r) {
        int cm = m0 + wm * 64 + mt * 16 + crow0 + r;
        Cf[(long)b * cBatch + (long)cm * N + cn] = acc[mt][nt][r] * scale;
      }
    }
  }
}

// ---------------------------------------------------------------------------
// Column softmax over q (axis=1) of scores[b][q][k], online max/sum.
// ---------------------------------------------------------------------------
__global__ __launch_bounds__(256) void softmax_col(const float* __restrict__ sc,
                                                   __bf16* __restrict__ attn) {
  __shared__ float sm[8][32], ss[8][32];
  const int b  = blockIdx.y;
  const int kk = threadIdx.x & 31;
  const int g  = threadIdx.x >> 5;
  const int k  = blockIdx.x * 32 + kk;
  const float* base = sc + (long)b * Sc * Sc + k;
  const int q0 = g * (Sc / 8), q1 = q0 + (Sc / 8);

  float m = -3.0e38f, s = 0.f;
  for (int q = q0; q < q1; ++q) {
    float v = base[(long)q * Sc];
    float mn = fmaxf(m, v);
    s = s * __expf(m - mn) + __expf(v - mn);
    m = mn;
  }
  sm[g][kk] = m;
  ss[g][kk] = s;
  __syncthreads();
  if (g == 0) {
    float M = sm[0][kk], S = ss[0][kk];
#pragma unroll
    for (int j = 1; j < 8; ++j) {
      float mj = sm[j][kk], sj = ss[j][kk];
      float mn = fmaxf(M, mj);
      S = S * __expf(M - mn) + sj * __expf(mj - mn);
      M = mn;
    }
    sm[0][kk] = M;
    ss[0][kk] = 1.0f / S;
  }
  __syncthreads();
  const float M = sm[0][kk], inv = ss[0][kk];
  __bf16* ab = attn + (long)b * Sc * Sc + k;
  for (int q = q0; q < q1; ++q) {
    float v = base[(long)q * Sc];
    ab[(long)q * Sc] = f2bf(__expf(v - M) * inv);
  }
}

// ---------------------------------------------------------------------------
extern "C" void kernel_launch(void* const* d_in, const int* in_sizes, int n_in,
                              void* d_out, int out_size, void* d_ws, size_t ws_size,
                              hipStream_t stream) {
  const float* x  = (const float*)d_in[0];
  const float* WQ = (const float*)d_in[1];
  const float* WK = (const float*)d_in[2];
  const float* WV = (const float*)d_in[3];
  float* out = (float*)d_out;
  char* ws = (char*)d_ws;
  const long MB = 1024L * 1024L;

  // Workspace layout (peak 160 MB). attn reuses the x region (x dead after S).
  __bf16* xhi  = (__bf16*)(ws + 0 * MB);     // 16 MB
  __bf16* xlo  = (__bf16*)(ws + 16 * MB);    // 16 MB
  __bf16* wqhi = (__bf16*)(ws + 32 * MB);    // 2 MB each (element-wise split)
  __bf16* wqlo = (__bf16*)(ws + 34 * MB);
  __bf16* wkhi = (__bf16*)(ws + 36 * MB);
  __bf16* wklo = (__bf16*)(ws + 38 * MB);
  __bf16* wvthi= (__bf16*)(ws + 40 * MB);    // transposed (hi used by V GEMM)
  __bf16* wvtlo= (__bf16*)(ws + 42 * MB);
  __bf16* gthi = (__bf16*)(ws + 44 * MB);    // 2 MB each: Gt = (WQ WK^T)^T
  __bf16* gtlo = (__bf16*)(ws + 46 * MB);
  __bf16* thi  = (__bf16*)(ws + 48 * MB);    // 16 MB each: T = x*G
  __bf16* tlo  = (__bf16*)(ws + 64 * MB);
  __bf16* vt   = (__bf16*)(ws + 80 * MB);    // 16 MB, [B][DK][S]
  float*  scs  = (float*)(ws + 96 * MB);     // 64 MB, [B][S][S]
  __bf16* attn = (__bf16*)(ws + 0 * MB);     // 32 MB, reuses x region

  cast_split<<<(int)((BSc * Dc) / 256), 256, 0, stream>>>(x, xhi, xlo);
  cast_split<<<(Dc * DKc) / 256, 256, 0, stream>>>(WQ, wqhi, wqlo);
  cast_split<<<(Dc * DKc) / 256, 256, 0, stream>>>(WK, wkhi, wklo);
  transpose_split<<<dim3(32, 32), dim3(32, 8), 0, stream>>>(WV, wvthi, wvtlo);

  // Gt[d][a] = G[a][d], G = WQ*WK^T: NT(A=WK, B=WQ) yields C[m][n]=G[n][m].
  gemm_tile<MODE_QK><<<dim3(DKc / 128, Dc / 128, 1), 256, 0, stream>>>(
      wkhi, wklo, wqhi, wqlo, nullptr, gthi, gtlo, 1.0f);

  // T = x*G: NT(A=x, B=Gt).  [8192 x 1024]
  gemm_tile<MODE_QK><<<dim3(DKc / 128, BSc / 128, 1), 256, 0, stream>>>(
      xhi, xlo, gthi, gtlo, nullptr, thi, tlo, 1.0f);

  // Vt = (x*WV)^T per batch.
  gemm_tile<MODE_V><<<dim3(DKc / 128, BSc / 128, 1), 256, 0, stream>>>(
      xhi, nullptr, wvthi, nullptr, nullptr, vt, nullptr, 1.0f);

  // S = T*x^T * scale.
  gemm_tile<MODE_S><<<dim3(Sc / 128, Sc / 128, Bc), 256, 0, stream>>>(
      thi, tlo, xhi, xlo, scs, nullptr, nullptr, 0.03125f);

  softmax_col<<<dim3(Sc / 32, Bc), 256, 0, stream>>>(scs, attn);

  gemm_tile<MODE_PV><<<dim3(DKc / 128, Sc / 128, Bc), 256, 0, stream>>>(
      attn, nullptr, vt, nullptr, out, nullptr, nullptr, 1.0f);
}

// Round 5
// 446.227 us; speedup vs baseline: 1.0616x; 1.0616x over previous
//
#include <hip/hip_runtime.h>

// Problem constants (fixed by the reference): B=4, S=2048, D=DK=1024.
constexpr int Bc  = 4;
constexpr int Sc  = 2048;
constexpr int Dc  = 1024;
constexpr int DKc = 1024;
constexpr long BSc = (long)Bc * Sc;      // 8192 flattened rows of x

typedef __attribute__((ext_vector_type(8))) __bf16 bf16x8;
typedef __attribute__((ext_vector_type(4))) __bf16 bf16x4;
typedef __attribute__((ext_vector_type(4))) float  floatx4;

__device__ inline __bf16 f2bf(float f) {
  unsigned u = __builtin_bit_cast(unsigned, f);
  u = (u + 0x7FFFu + ((u >> 16) & 1u)) >> 16;      // RNE
  unsigned short s = (unsigned short)u;
  return __builtin_bit_cast(__bf16, s);
}
__device__ inline float bf2f(__bf16 h) {
  unsigned u = ((unsigned)__builtin_bit_cast(unsigned short, h)) << 16;
  return __builtin_bit_cast(float, u);
}

// async global->LDS, 16B per lane. lds base must be wave-uniform; HW scatters
// lane i's 16B to ldsbase + i*16.
__device__ inline void stage16(const __bf16* g, __bf16* l) {
  __builtin_amdgcn_global_load_lds(
      (const __attribute__((address_space(1))) unsigned int*)g,
      (__attribute__((address_space(3))) unsigned int*)l, 16, 0, 0);
}

// ---------------------------------------------------------------------------
// Merged fp32 -> hi/lo bf16 split for x (32768 blks), WQ (4096), WK (4096).
// ---------------------------------------------------------------------------
__global__ __launch_bounds__(256) void cast_all(
    const float* __restrict__ x,  __bf16* __restrict__ xhi, __bf16* __restrict__ xlo,
    const float* __restrict__ wq, __bf16* __restrict__ qhi, __bf16* __restrict__ qlo,
    const float* __restrict__ wk, __bf16* __restrict__ khi, __bf16* __restrict__ klo) {
  long blk = blockIdx.x;
  const float* in; __bf16 *hi, *lo; long base;
  if (blk < 32768)      { in = x;  hi = xhi; lo = xlo; base = blk * 256; }
  else if (blk < 36864) { in = wq; hi = qhi; lo = qlo; base = (blk - 32768) * 256; }
  else                  { in = wk; hi = khi; lo = klo; base = (blk - 36864) * 256; }
  long i = base + threadIdx.x;
  float f = in[i];
  __bf16 h = f2bf(f);
  hi[i] = h;
  lo[i] = f2bf(f - bf2f(h));
}

// ---------------------------------------------------------------------------
// W [D][DK] fp32 -> Wt hi/lo [DK][D] bf16 (transposed split). For WV only.
// ---------------------------------------------------------------------------
__global__ __launch_bounds__(256) void transpose_split(const float* __restrict__ in,
                                                       __bf16* __restrict__ hi,
                                                       __bf16* __restrict__ lo) {
  __shared__ float tile[32][33];
  int xI = blockIdx.x * 32 + threadIdx.x;
  int yI = blockIdx.y * 32 + threadIdx.y;
#pragma unroll
  for (int j = 0; j < 32; j += 8)
    tile[threadIdx.y + j][threadIdx.x] = in[(long)(yI + j) * DKc + xI];
  __syncthreads();
  int xO = blockIdx.y * 32 + threadIdx.x;
  int yO = blockIdx.x * 32 + threadIdx.y;
#pragma unroll
  for (int j = 0; j < 32; j += 8) {
    float v = tile[threadIdx.x][threadIdx.y + j];
    long idx = (long)(yO + j) * Dc + xO;
    __bf16 h = f2bf(v);
    hi[idx] = h;
    lo[idx] = f2bf(v - bf2f(h));
  }
}

// ---------------------------------------------------------------------------
// m97-structure NT MFMA GEMM: C[M][N] = A[M][K] * Bt[N][K]^T, row-major bf16.
// 128x128 block tile, 4 waves 2x2, each 64x64 (4x4 accs of 16x16x32).
// BK=32 staged via global_load_lds width=16; XOR-swizzled on the global
// source side (round-3: conflicts 8.4M -> 0).
//
// MODE_QK: split (3 MFMA), bf16 hi+lo store via LDS round-trip (coalesced).
// MODE_V : plain, TRANSPOSED store via LDS -> Vt[b][n][seq]
// MODE_S : split, fp32 store * scale, z=B; epilogue ALSO reduces its tile to
//          per-column (max, expsum) partials -> Pmax/Psum[b][qtile][k]
//          (softmax phase-1 fused; round-5).
// MODE_PV: plain, fp32 store, z=B
// ---------------------------------------------------------------------------
enum { MODE_QK = 0, MODE_V = 1, MODE_S = 2, MODE_PV = 3 };

template <int MODE>
__global__ __launch_bounds__(256) void gemm_tile(
    const __bf16* __restrict__ Ahi, const __bf16* __restrict__ Alo,
    const __bf16* __restrict__ Bhi, const __bf16* __restrict__ Blo,
    float* __restrict__ Cf, __bf16* __restrict__ Chi, __bf16* __restrict__ Clo,
    float* __restrict__ Pmax, float* __restrict__ Psum, float scale) {
  constexpr bool SPLIT = (MODE == MODE_QK || MODE == MODE_S);
  constexpr int  K = (MODE == MODE_PV) ? Sc : Dc;
  constexpr int  N = (MODE == MODE_S) ? Sc : DKc;
  constexpr long aBatch = (MODE == MODE_S) ? (long)Sc * DKc
                        : (MODE == MODE_PV) ? (long)Sc * Sc : 0;
  constexpr long bBatch = (MODE == MODE_S) ? (long)Sc * DKc
                        : (MODE == MODE_PV) ? (long)DKc * Sc : 0;
  constexpr long cBatch = (MODE == MODE_S) ? (long)Sc * Sc
                        : (MODE == MODE_PV) ? (long)Sc * DKc : 0;
  constexpr int SMEM = (SPLIT || MODE == MODE_V) ? 32768 : 16384;
  __shared__ __align__(16) char smem[SMEM];
  __bf16* sAh = (__bf16*)smem;           // [128][32] (chunk-swizzled)
  __bf16* sBh = sAh + 128 * 32;
  __bf16* sAl = sBh + 128 * 32;          // split only
  __bf16* sBl = sAl + 128 * 32;

  const int b    = blockIdx.z;
  const int wave = threadIdx.x >> 6;
  const int lane = threadIdx.x & 63;
  const int wm   = wave >> 1;            // 0..1
  const int wn   = wave & 1;             // 0..1
  const int m0   = blockIdx.y * 128;
  const int n0   = blockIdx.x * 128;

  const __bf16* Ab  = Ahi + (long)b * aBatch + (long)m0 * K;
  const __bf16* Bb  = Bhi + (long)b * bBatch + (long)n0 * K;
  const __bf16* Abl = SPLIT ? Alo + (long)b * aBatch + (long)m0 * K : nullptr;
  const __bf16* Bbl = SPLIT ? Blo + (long)b * bBatch + (long)n0 * K : nullptr;

  // Staging: wave w stages rows [w*32, w*32+32); lane (r,c) loads global
  // chunk c^((r>>1)&3) -> physical LDS slot base + lane*16B.
  const int sr   = lane >> 2;                       // 0..15
  const int sc_  = lane & 3;                        // 0..3
  const int scol = (sc_ ^ ((sr >> 1) & 3)) * 8;     // swizzled global col

  floatx4 acc[4][4];
  const floatx4 zero = {0.f, 0.f, 0.f, 0.f};
#pragma unroll
  for (int i = 0; i < 4; ++i)
#pragma unroll
    for (int j = 0; j < 4; ++j) acc[i][j] = zero;

  const int frow = lane & 15;
  // Fragment read: logical chunk = lane>>4; physical chunk is XOR'd by row.
  const int pko = ((lane >> 4) ^ ((frow >> 1) & 3)) * 8;

#pragma unroll 1
  for (int k0 = 0; k0 < K; k0 += 32) {
#pragma unroll
    for (int i = 0; i < 2; ++i) {
      const int rb = wave * 32 + i * 16;            // wave-uniform row base
      const long go = (long)(rb + sr) * K + k0 + scol;
      stage16(Ab + go, sAh + rb * 32);
      stage16(Bb + go, sBh + rb * 32);
      if constexpr (SPLIT) {
        stage16(Abl + go, sAl + rb * 32);
        stage16(Bbl + go, sBl + rb * 32);
      }
    }
    __syncthreads();

    bf16x8 af[4], bfr[4], afl[4], bfl[4];
#pragma unroll
    for (int t = 0; t < 4; ++t) {
      af[t]  = *(const bf16x8*)(sAh + (wm * 64 + t * 16 + frow) * 32 + pko);
      bfr[t] = *(const bf16x8*)(sBh + (wn * 64 + t * 16 + frow) * 32 + pko);
      if constexpr (SPLIT) {
        afl[t] = *(const bf16x8*)(sAl + (wm * 64 + t * 16 + frow) * 32 + pko);
        bfl[t] = *(const bf16x8*)(sBl + (wn * 64 + t * 16 + frow) * 32 + pko);
      }
    }
#pragma unroll
    for (int mt = 0; mt < 4; ++mt)
#pragma unroll
      for (int nt = 0; nt < 4; ++nt) {
        acc[mt][nt] = __builtin_amdgcn_mfma_f32_16x16x32_bf16(af[mt], bfr[nt], acc[mt][nt], 0, 0, 0);
        if constexpr (SPLIT) {
          acc[mt][nt] = __builtin_amdgcn_mfma_f32_16x16x32_bf16(af[mt], bfl[nt], acc[mt][nt], 0, 0, 0);
          acc[mt][nt] = __builtin_amdgcn_mfma_f32_16x16x32_bf16(afl[mt], bfr[nt], acc[mt][nt], 0, 0, 0);
        }
      }
    __syncthreads();
  }

  // Epilogue. D layout: col=lane&15, row=(lane>>4)*4+reg (m89/m91-verified).
  const int crow0 = (lane >> 4) * 4;
  const int ccol  = lane & 15;

  if constexpr (MODE == MODE_QK) {
    // bf16 hi/lo store via LDS round-trip: 2B scattered -> 16B coalesced.
    __bf16* sT = (__bf16*)smem;          // [128][128] bf16 = 32KB
#pragma unroll 1
    for (int pass = 0; pass < 2; ++pass) {
      __syncthreads();
#pragma unroll
      for (int nt = 0; nt < 4; ++nt) {
        int col = wn * 64 + nt * 16 + ccol;
#pragma unroll
        for (int mt = 0; mt < 4; ++mt) {
          int row = wm * 64 + mt * 16 + crow0;
#pragma unroll
          for (int r = 0; r < 4; ++r) {
            float v = acc[mt][nt][r] * scale;
            __bf16 h = f2bf(v);
            sT[(row + r) * 128 + col] = pass ? f2bf(v - bf2f(h)) : h;
          }
        }
      }
      __syncthreads();
      __bf16* dst = pass ? Clo : Chi;
#pragma unroll
      for (int c = 0; c < 8; ++c) {
        int flat = c * 2048 + threadIdx.x * 8;
        int row = flat >> 7, col = flat & 127;
        *(bf16x8*)(dst + (long)(m0 + row) * N + n0 + col) = *(const bf16x8*)(sT + flat);
      }
    }
    return;
  }

  if constexpr (MODE == MODE_V) {
    // Transpose through LDS (staging dead; reuse full 32KB as sT[128][128]).
    __bf16* sT = (__bf16*)smem;
#pragma unroll
    for (int nt = 0; nt < 4; ++nt) {
      int nl = wn * 64 + nt * 16 + ccol;
#pragma unroll
      for (int mt = 0; mt < 4; ++mt) {
        int ml = wm * 64 + mt * 16 + crow0;
#pragma unroll
        for (int r = 0; r < 4; ++r)
          sT[(long)nl * 128 + ml + r] = f2bf(acc[mt][nt][r]);
      }
    }
    __syncthreads();
    const int bb   = m0 >> 11;          // tile fully within one batch
    const int seq0 = m0 & (Sc - 1);
    __bf16* dst = Chi + (long)bb * DKc * Sc + seq0;
#pragma unroll
    for (int c = 0; c < 8; ++c) {
      int flat = c * 2048 + threadIdx.x * 8;   // elements; 16B per thread
      int row = flat >> 7, col = flat & 127;
      *(bf16x8*)(dst + (long)(n0 + row) * Sc + col) = *(const bf16x8*)(sT + flat);
    }
    return;
  }

  // MODE_S / MODE_PV: direct fp32 store.
#pragma unroll
  for (int nt = 0; nt < 4; ++nt) {
    int cn = n0 + wn * 64 + nt * 16 + ccol;
#pragma unroll
    for (int mt = 0; mt < 4; ++mt) {
#pragma unroll
      for (int r = 0; r < 4; ++r) {
        int cm = m0 + wm * 64 + mt * 16 + crow0 + r;
        Cf[(long)b * cBatch + (long)cm * N + cn] = acc[mt][nt][r] * scale;
      }
    }
  }

  if constexpr (MODE == MODE_S) {
    // Fused softmax phase-1: column (max, expsum) over this tile's 128 rows.
    float cm[4], cs[4];
#pragma unroll
    for (int nt = 0; nt < 4; ++nt) {
      float mx = -3.0e38f;
#pragma unroll
      for (int mt = 0; mt < 4; ++mt)
#pragma unroll
        for (int r = 0; r < 4; ++r) mx = fmaxf(mx, acc[mt][nt][r] * scale);
      float sm = 0.f;
#pragma unroll
      for (int mt = 0; mt < 4; ++mt)
#pragma unroll
        for (int r = 0; r < 4; ++r) sm += __expf(acc[mt][nt][r] * scale - mx);
      cm[nt] = mx; cs[nt] = sm;
    }
    // Butterfly across the 4 lane-groups sharing a column (lane ^16, ^32).
#pragma unroll
    for (int off = 16; off <= 32; off <<= 1) {
#pragma unroll
      for (int nt = 0; nt < 4; ++nt) {
        float om = __shfl_xor(cm[nt], off, 64);
        float os = __shfl_xor(cs[nt], off, 64);
        float nm = fmaxf(cm[nt], om);
        cs[nt] = cs[nt] * __expf(cm[nt] - nm) + os * __expf(om - nm);
        cm[nt] = nm;
      }
    }
    // Cross-wave (wm=0 vs 1) via LDS (staging is dead).
    float* smax = (float*)smem;          // [2][128]
    float* ssum = smax + 256;
    if (lane < 16) {
#pragma unroll
      for (int nt = 0; nt < 4; ++nt) {
        int c = wn * 64 + nt * 16 + lane;
        smax[wm * 128 + c] = cm[nt];
        ssum[wm * 128 + c] = cs[nt];
      }
    }
    __syncthreads();
    int tid = threadIdx.x;
    if (tid < 128) {
      float ma = smax[tid], mb = smax[128 + tid];
      float nm = fmaxf(ma, mb);
      float s  = ssum[tid] * __expf(ma - nm) + ssum[128 + tid] * __expf(mb - nm);
      long o = ((long)b * 16 + blockIdx.y) * Sc + n0 + tid;
      Pmax[o] = nm;
      Psum[o] = s;
    }
  }
}

// ---------------------------------------------------------------------------
// Fold 16 q-tile partials -> M_k, 1/Z_k.  Grid: B*S/256 = 32 blocks.
// ---------------------------------------------------------------------------
__global__ __launch_bounds__(256) void softmax_reduce(const float* __restrict__ Pmax,
                                                      const float* __restrict__ Psum,
                                                      float* __restrict__ Mk,
                                                      float* __restrict__ Ck) {
  int idx = blockIdx.x * 256 + threadIdx.x;   // b*2048 + k
  int b = idx >> 11, k = idx & (Sc - 1);
  const float* pm = Pmax + (long)b * 16 * Sc + k;
  const float* ps = Psum + (long)b * 16 * Sc + k;
  float M = -3.0e38f, S = 0.f;
#pragma unroll
  for (int t = 0; t < 16; ++t) {
    float m = pm[(long)t * Sc], s = ps[(long)t * Sc];
    float nm = fmaxf(M, m);
    S = S * __expf(M - nm) + s * __expf(m - nm);
    M = nm;
  }
  Mk[idx] = M;
  Ck[idx] = 1.0f / S;
}

// ---------------------------------------------------------------------------
// attn[b][q][k] = exp(scs - M_k) * C_k, fully coalesced float4/bf16x4.
// Grid: B*S*S/1024 = 16384 blocks; thread handles 4 consecutive k.
// ---------------------------------------------------------------------------
__global__ __launch_bounds__(256) void softmax_apply(const float* __restrict__ scs,
                                                     const float* __restrict__ Mk,
                                                     const float* __restrict__ Ck,
                                                     __bf16* __restrict__ attn) {
  long t   = (long)blockIdx.x * 256 + threadIdx.x;
  long row = t >> 9;                       // b*2048 + q
  int  kc  = (int)(t & 511) << 2;
  int  b   = (int)(row >> 11);
  const float4 s4 = *(const float4*)(scs + (row << 11) + kc);
  const float4 m4 = *(const float4*)(Mk + ((long)b << 11) + kc);
  const float4 c4 = *(const float4*)(Ck + ((long)b << 11) + kc);
  bf16x4 o;
  o[0] = f2bf(__expf(s4.x - m4.x) * c4.x);
  o[1] = f2bf(__expf(s4.y - m4.y) * c4.y);
  o[2] = f2bf(__expf(s4.z - m4.z) * c4.z);
  o[3] = f2bf(__expf(s4.w - m4.w) * c4.w);
  *(bf16x4*)(attn + (row << 11) + kc) = o;
}

// ---------------------------------------------------------------------------
extern "C" void kernel_launch(void* const* d_in, const int* in_sizes, int n_in,
                              void* d_out, int out_size, void* d_ws, size_t ws_size,
                              hipStream_t stream) {
  const float* x  = (const float*)d_in[0];
  const float* WQ = (const float*)d_in[1];
  const float* WK = (const float*)d_in[2];
  const float* WV = (const float*)d_in[3];
  float* out = (float*)d_out;
  char* ws = (char*)d_ws;
  const long MB = 1024L * 1024L;

  // Workspace layout (peak ~164 MB). attn reuses the x region (x dead after S).
  __bf16* xhi  = (__bf16*)(ws + 0 * MB);     // 16 MB
  __bf16* xlo  = (__bf16*)(ws + 16 * MB);    // 16 MB
  __bf16* wqhi = (__bf16*)(ws + 32 * MB);    // 2 MB each (element-wise split)
  __bf16* wqlo = (__bf16*)(ws + 34 * MB);
  __bf16* wkhi = (__bf16*)(ws + 36 * MB);
  __bf16* wklo = (__bf16*)(ws + 38 * MB);
  __bf16* wvthi= (__bf16*)(ws + 40 * MB);    // transposed (hi used by V GEMM)
  __bf16* wvtlo= (__bf16*)(ws + 42 * MB);
  __bf16* gthi = (__bf16*)(ws + 44 * MB);    // 2 MB each: Gt = (WQ WK^T)^T
  __bf16* gtlo = (__bf16*)(ws + 46 * MB);
  __bf16* thi  = (__bf16*)(ws + 48 * MB);    // 16 MB each: T = x*G
  __bf16* tlo  = (__bf16*)(ws + 64 * MB);
  __bf16* vt   = (__bf16*)(ws + 80 * MB);    // 16 MB, [B][DK][S]
  float*  scs  = (float*)(ws + 96 * MB);     // 64 MB, [B][S][S]
  float*  pmax = (float*)(ws + 160 * MB);    // 512 KB, [B][16][S]
  float*  psum = (float*)(ws + 161 * MB);    // 512 KB
  float*  Mk   = (float*)(ws + 162 * MB);    // 32 KB, [B][S]
  float*  Ck   = (float*)(ws + 163 * MB);    // 32 KB
  __bf16* attn = (__bf16*)(ws + 0 * MB);     // 32 MB, reuses x region

  cast_all<<<40960, 256, 0, stream>>>(x, xhi, xlo, WQ, wqhi, wqlo, WK, wkhi, wklo);
  transpose_split<<<dim3(32, 32), dim3(32, 8), 0, stream>>>(WV, wvthi, wvtlo);

  // Gt[d][a] = G[a][d], G = WQ*WK^T: NT(A=WK, B=WQ) yields C[m][n]=G[n][m].
  gemm_tile<MODE_QK><<<dim3(DKc / 128, Dc / 128, 1), 256, 0, stream>>>(
      wkhi, wklo, wqhi, wqlo, nullptr, gthi, gtlo, nullptr, nullptr, 1.0f);

  // T = x*G: NT(A=x, B=Gt).  [8192 x 1024]
  gemm_tile<MODE_QK><<<dim3(DKc / 128, BSc / 128, 1), 256, 0, stream>>>(
      xhi, xlo, gthi, gtlo, nullptr, thi, tlo, nullptr, nullptr, 1.0f);

  // Vt = (x*WV)^T per batch.
  gemm_tile<MODE_V><<<dim3(DKc / 128, BSc / 128, 1), 256, 0, stream>>>(
      xhi, nullptr, wvthi, nullptr, nullptr, vt, nullptr, nullptr, nullptr, 1.0f);

  // S = T*x^T * scale, with fused per-tile column max/expsum partials.
  gemm_tile<MODE_S><<<dim3(Sc / 128, Sc / 128, Bc), 256, 0, stream>>>(
      thi, tlo, xhi, xlo, scs, nullptr, nullptr, pmax, psum, 0.03125f);

  softmax_reduce<<<32, 256, 0, stream>>>(pmax, psum, Mk, Ck);
  softmax_apply<<<16384, 256, 0, stream>>>(scs, Mk, Ck, attn);

  gemm_tile<MODE_PV><<<dim3(DKc / 128, Sc / 128, Bc), 256, 0, stream>>>(
      attn, nullptr, vt, nullptr, out, nullptr, nullptr, nullptr, nullptr, 1.0f);
}

// Round 6
// 440.503 us; speedup vs baseline: 1.0754x; 1.0130x over previous
//
#include <hip/hip_runtime.h>

// Problem constants (fixed by the reference): B=4, S=2048, D=DK=1024.
constexpr int Bc  = 4;
constexpr int Sc  = 2048;
constexpr int Dc  = 1024;
constexpr int DKc = 1024;
constexpr long BSc = (long)Bc * Sc;      // 8192 flattened rows of x

typedef __attribute__((ext_vector_type(8))) __bf16 bf16x8;
typedef __attribute__((ext_vector_type(4))) float  floatx4;

__device__ inline __bf16 f2bf(float f) {
  unsigned u = __builtin_bit_cast(unsigned, f);
  u = (u + 0x7FFFu + ((u >> 16) & 1u)) >> 16;      // RNE
  unsigned short s = (unsigned short)u;
  return __builtin_bit_cast(__bf16, s);
}
__device__ inline float bf2f(__bf16 h) {
  unsigned u = ((unsigned)__builtin_bit_cast(unsigned short, h)) << 16;
  return __builtin_bit_cast(float, u);
}

// async global->LDS, 16B per lane. lds base must be wave-uniform; HW scatters
// lane i's 16B to ldsbase + i*16.
__device__ inline void stage16(const __bf16* g, __bf16* l) {
  __builtin_amdgcn_global_load_lds(
      (const __attribute__((address_space(1))) unsigned int*)g,
      (__attribute__((address_space(3))) unsigned int*)l, 16, 0, 0);
}

// ---------------------------------------------------------------------------
// Merged fp32 -> hi/lo bf16 split for x (32768 blks), WQ (4096), WK (4096).
// ---------------------------------------------------------------------------
__global__ __launch_bounds__(256) void cast_all(
    const float* __restrict__ x,  __bf16* __restrict__ xhi, __bf16* __restrict__ xlo,
    const float* __restrict__ wq, __bf16* __restrict__ qhi, __bf16* __restrict__ qlo,
    const float* __restrict__ wk, __bf16* __restrict__ khi, __bf16* __restrict__ klo) {
  long blk = blockIdx.x;
  const float* in; __bf16 *hi, *lo; long base;
  if (blk < 32768)      { in = x;  hi = xhi; lo = xlo; base = blk * 256; }
  else if (blk < 36864) { in = wq; hi = qhi; lo = qlo; base = (blk - 32768) * 256; }
  else                  { in = wk; hi = khi; lo = klo; base = (blk - 36864) * 256; }
  long i = base + threadIdx.x;
  float f = in[i];
  __bf16 h = f2bf(f);
  hi[i] = h;
  lo[i] = f2bf(f - bf2f(h));
}

// ---------------------------------------------------------------------------
// W [D][DK] fp32 -> Wt hi/lo [DK][D] bf16 (transposed split). For WV only.
// ---------------------------------------------------------------------------
__global__ __launch_bounds__(256) void transpose_split(const float* __restrict__ in,
                                                       __bf16* __restrict__ hi,
                                                       __bf16* __restrict__ lo) {
  __shared__ float tile[32][33];
  int xI = blockIdx.x * 32 + threadIdx.x;
  int yI = blockIdx.y * 32 + threadIdx.y;
#pragma unroll
  for (int j = 0; j < 32; j += 8)
    tile[threadIdx.y + j][threadIdx.x] = in[(long)(yI + j) * DKc + xI];
  __syncthreads();
  int xO = blockIdx.y * 32 + threadIdx.x;
  int yO = blockIdx.x * 32 + threadIdx.y;
#pragma unroll
  for (int j = 0; j < 32; j += 8) {
    float v = tile[threadIdx.x][threadIdx.y + j];
    long idx = (long)(yO + j) * Dc + xO;
    __bf16 h = f2bf(v);
    hi[idx] = h;
    lo[idx] = f2bf(v - bf2f(h));
  }
}

// ---------------------------------------------------------------------------
// m97-structure NT MFMA GEMM: C[M][N] = A[M][K] * Bt[N][K]^T, row-major bf16.
// 128x128 tile, 4 waves 2x2, each 64x64 (4x4 accs of 16x16x32). BK=32 via
// global_load_lds width=16, XOR chunk swizzle on the global source side
// (round-3: conflicts 8.4M -> 0).
//
// MODE_QK: split (3 MFMA), bf16 hi+lo store via LDS round-trip.
// MODE_V : plain, TRANSPOSED store via LDS -> Vt[b][n][seq]
// MODE_S : split; epilogue computes per-column tile max M_t, stores
//          p = exp(s - M_t) in BF16 (via LDS round-trip) + Pmax/Psum partials.
//          No fp32 score matrix is materialized (round-6).
// MODE_PV: plain; A staged MANUALLY: attn = p * ffac[qtile][k] computed on
//          the fly during LDS staging (softmax_apply fused away).
// ---------------------------------------------------------------------------
enum { MODE_QK = 0, MODE_V = 1, MODE_S = 2, MODE_PV = 3 };

template <int MODE>
__global__ __launch_bounds__(256) void gemm_tile(
    const __bf16* __restrict__ Ahi, const __bf16* __restrict__ Alo,
    const __bf16* __restrict__ Bhi, const __bf16* __restrict__ Blo,
    float* __restrict__ Cf, __bf16* __restrict__ Chi, __bf16* __restrict__ Clo,
    float* __restrict__ Pmax, float* __restrict__ Psum,
    const float* __restrict__ Ffac, float scale) {
  constexpr bool SPLIT = (MODE == MODE_QK || MODE == MODE_S);
  constexpr int  K = (MODE == MODE_PV) ? Sc : Dc;
  constexpr int  N = (MODE == MODE_S) ? Sc : DKc;
  constexpr long aBatch = (MODE == MODE_S) ? (long)Sc * DKc
                        : (MODE == MODE_PV) ? (long)Sc * Sc : 0;
  constexpr long bBatch = (MODE == MODE_S) ? (long)Sc * DKc
                        : (MODE == MODE_PV) ? (long)DKc * Sc : 0;
  constexpr long cBatch = (MODE == MODE_S) ? (long)Sc * Sc
                        : (MODE == MODE_PV) ? (long)Sc * DKc : 0;
  constexpr int SMEM = (SPLIT || MODE == MODE_V) ? 32768 : 16384;
  __shared__ __align__(16) char smem[SMEM];
  __bf16* sAh = (__bf16*)smem;           // [128][32] (chunk-swizzled)
  __bf16* sBh = sAh + 128 * 32;
  __bf16* sAl = sBh + 128 * 32;          // split only
  __bf16* sBl = sAl + 128 * 32;

  const int b    = blockIdx.z;
  const int wave = threadIdx.x >> 6;
  const int lane = threadIdx.x & 63;
  const int wm   = wave >> 1;            // 0..1
  const int wn   = wave & 1;             // 0..1
  const int m0   = blockIdx.y * 128;
  const int n0   = blockIdx.x * 128;

  const __bf16* Ab  = Ahi + (long)b * aBatch + (long)m0 * K;
  const __bf16* Bb  = Bhi + (long)b * bBatch + (long)n0 * K;
  const __bf16* Abl = SPLIT ? Alo + (long)b * aBatch + (long)m0 * K : nullptr;
  const __bf16* Bbl = SPLIT ? Blo + (long)b * bBatch + (long)n0 * K : nullptr;
  const float*  Fb  = (MODE == MODE_PV)
                    ? Ffac + ((long)b * 16 + blockIdx.y) * Sc : nullptr;

  // Async staging: wave w stages rows [w*32,w*32+32); lane (r,c) loads global
  // chunk c^((r>>1)&3) -> physical LDS slot base + lane*16B.
  const int sr   = lane >> 2;                       // 0..15
  const int sc_  = lane & 3;                        // 0..3
  const int scol = (sc_ ^ ((sr >> 1) & 3)) * 8;     // swizzled global col

  floatx4 acc[4][4];
  const floatx4 zero = {0.f, 0.f, 0.f, 0.f};
#pragma unroll
  for (int i = 0; i < 4; ++i)
#pragma unroll
    for (int j = 0; j < 4; ++j) acc[i][j] = zero;

  const int frow = lane & 15;
  // Fragment read: logical chunk = lane>>4; physical chunk is XOR'd by row.
  const int pko = ((lane >> 4) ^ ((frow >> 1) & 3)) * 8;

#pragma unroll 1
  for (int k0 = 0; k0 < K; k0 += 32) {
    if constexpr (MODE == MODE_PV) {
      // B (vt) async as usual.
#pragma unroll
      for (int i = 0; i < 2; ++i) {
        const int rb = wave * 32 + i * 16;
        stage16(Bb + (long)(rb + sr) * K + k0 + scol, sBh + rb * 32);
      }
      // A manual: attn chunk = p * ffac, conflict-free lane-sequential write.
      const int tr = threadIdx.x >> 2;              // 0..63
      const int pc = threadIdx.x & 3;               // physical chunk
#pragma unroll
      for (int h = 0; h < 2; ++h) {
        int r  = h * 64 + tr;
        int lc = pc ^ ((r >> 1) & 3);               // logical chunk
        bf16x8 pv = *(const bf16x8*)(Ab + (long)r * K + k0 + lc * 8);
        const float* fp = Fb + k0 + lc * 8;
        bf16x8 o;
#pragma unroll
        for (int j = 0; j < 8; ++j) o[j] = f2bf(bf2f(pv[j]) * fp[j]);
        *(bf16x8*)(sAh + r * 32 + pc * 8) = o;
      }
    } else {
#pragma unroll
      for (int i = 0; i < 2; ++i) {
        const int rb = wave * 32 + i * 16;          // wave-uniform row base
        const long go = (long)(rb + sr) * K + k0 + scol;
        stage16(Ab + go, sAh + rb * 32);
        stage16(Bb + go, sBh + rb * 32);
        if constexpr (SPLIT) {
          stage16(Abl + go, sAl + rb * 32);
          stage16(Bbl + go, sBl + rb * 32);
        }
      }
    }
    __syncthreads();

    bf16x8 af[4], bfr[4], afl[4], bfl[4];
#pragma unroll
    for (int t = 0; t < 4; ++t) {
      af[t]  = *(const bf16x8*)(sAh + (wm * 64 + t * 16 + frow) * 32 + pko);
      bfr[t] = *(const bf16x8*)(sBh + (wn * 64 + t * 16 + frow) * 32 + pko);
      if constexpr (SPLIT) {
        afl[t] = *(const bf16x8*)(sAl + (wm * 64 + t * 16 + frow) * 32 + pko);
        bfl[t] = *(const bf16x8*)(sBl + (wn * 64 + t * 16 + frow) * 32 + pko);
      }
    }
#pragma unroll
    for (int mt = 0; mt < 4; ++mt)
#pragma unroll
      for (int nt = 0; nt < 4; ++nt) {
        acc[mt][nt] = __builtin_amdgcn_mfma_f32_16x16x32_bf16(af[mt], bfr[nt], acc[mt][nt], 0, 0, 0);
        if constexpr (SPLIT) {
          acc[mt][nt] = __builtin_amdgcn_mfma_f32_16x16x32_bf16(af[mt], bfl[nt], acc[mt][nt], 0, 0, 0);
          acc[mt][nt] = __builtin_amdgcn_mfma_f32_16x16x32_bf16(afl[mt], bfr[nt], acc[mt][nt], 0, 0, 0);
        }
      }
    __syncthreads();
  }

  // Epilogue. D layout: col=lane&15, row=(lane>>4)*4+reg (m89/m91-verified).
  const int crow0 = (lane >> 4) * 4;
  const int ccol  = lane & 15;
  const int tid   = threadIdx.x;

  if constexpr (MODE == MODE_QK) {
    // bf16 hi/lo store via LDS round-trip: 2B scattered -> 16B coalesced.
    __bf16* sT = (__bf16*)smem;          // [128][128] bf16 = 32KB
#pragma unroll 1
    for (int pass = 0; pass < 2; ++pass) {
      __syncthreads();
#pragma unroll
      for (int nt = 0; nt < 4; ++nt) {
        int col = wn * 64 + nt * 16 + ccol;
#pragma unroll
        for (int mt = 0; mt < 4; ++mt) {
          int row = wm * 64 + mt * 16 + crow0;
#pragma unroll
          for (int r = 0; r < 4; ++r) {
            float v = acc[mt][nt][r] * scale;
            __bf16 h = f2bf(v);
            sT[(row + r) * 128 + col] = pass ? f2bf(v - bf2f(h)) : h;
          }
        }
      }
      __syncthreads();
      __bf16* dst = pass ? Clo : Chi;
#pragma unroll
      for (int c = 0; c < 8; ++c) {
        int flat = c * 2048 + tid * 8;
        int row = flat >> 7, col = flat & 127;
        *(bf16x8*)(dst + (long)(m0 + row) * N + n0 + col) = *(const bf16x8*)(sT + flat);
      }
    }
    return;
  }

  if constexpr (MODE == MODE_V) {
    // Transpose through LDS (staging dead; reuse full 32KB as sT[128][128]).
    __bf16* sT = (__bf16*)smem;
#pragma unroll
    for (int nt = 0; nt < 4; ++nt) {
      int nl = wn * 64 + nt * 16 + ccol;
#pragma unroll
      for (int mt = 0; mt < 4; ++mt) {
        int ml = wm * 64 + mt * 16 + crow0;
#pragma unroll
        for (int r = 0; r < 4; ++r)
          sT[(long)nl * 128 + ml + r] = f2bf(acc[mt][nt][r]);
      }
    }
    __syncthreads();
    const int bb   = m0 >> 11;          // tile fully within one batch
    const int seq0 = m0 & (Sc - 1);
    __bf16* dst = Chi + (long)bb * DKc * Sc + seq0;
#pragma unroll
    for (int c = 0; c < 8; ++c) {
      int flat = c * 2048 + tid * 8;    // elements; 16B per thread
      int row = flat >> 7, col = flat & 127;
      *(bf16x8*)(dst + (long)(n0 + row) * Sc + col) = *(const bf16x8*)(sT + flat);
    }
    return;
  }

  if constexpr (MODE == MODE_S) {
    // (1) per-column tile max over 128 rows.
    float cm[4];
#pragma unroll
    for (int nt = 0; nt < 4; ++nt) {
      float mx = -3.0e38f;
#pragma unroll
      for (int mt = 0; mt < 4; ++mt)
#pragma unroll
        for (int r = 0; r < 4; ++r) mx = fmaxf(mx, acc[mt][nt][r] * scale);
      cm[nt] = mx;
    }
#pragma unroll
    for (int off = 16; off <= 32; off <<= 1)
#pragma unroll
      for (int nt = 0; nt < 4; ++nt)
        cm[nt] = fmaxf(cm[nt], __shfl_xor(cm[nt], off, 64));
    float* smax = (float*)smem;          // [2][128]
    float* ssum = smax + 256;
    if (lane < 16)
#pragma unroll
      for (int nt = 0; nt < 4; ++nt)
        smax[wm * 128 + wn * 64 + nt * 16 + lane] = cm[nt];
    __syncthreads();
    float mfin[4];
#pragma unroll
    for (int nt = 0; nt < 4; ++nt) {
      int c = wn * 64 + nt * 16 + ccol;
      mfin[nt] = fmaxf(smax[c], smax[128 + c]);
    }
    // (2) column expsum vs tile max.
    float ps[4];
#pragma unroll
    for (int nt = 0; nt < 4; ++nt) {
      float s = 0.f;
#pragma unroll
      for (int mt = 0; mt < 4; ++mt)
#pragma unroll
        for (int r = 0; r < 4; ++r)
          s += __expf(acc[mt][nt][r] * scale - mfin[nt]);
      ps[nt] = s;
    }
#pragma unroll
    for (int off = 16; off <= 32; off <<= 1)
#pragma unroll
      for (int nt = 0; nt < 4; ++nt) ps[nt] += __shfl_xor(ps[nt], off, 64);
    if (lane < 16)
#pragma unroll
      for (int nt = 0; nt < 4; ++nt)
        ssum[wm * 128 + wn * 64 + nt * 16 + lane] = ps[nt];
    __syncthreads();
    if (tid < 128) {
      long o = ((long)b * 16 + blockIdx.y) * Sc + n0 + tid;
      Pmax[o] = fmaxf(smax[tid], smax[128 + tid]);
      Psum[o] = ssum[tid] + ssum[128 + tid];
    }
    __syncthreads();                     // smax/ssum dead; reuse as sT
    // (3) p = exp(s - M_t) -> bf16, LDS round-trip, coalesced store.
    __bf16* sT = (__bf16*)smem;
#pragma unroll
    for (int nt = 0; nt < 4; ++nt) {
      int col = wn * 64 + nt * 16 + ccol;
#pragma unroll
      for (int mt = 0; mt < 4; ++mt) {
        int row = wm * 64 + mt * 16 + crow0;
#pragma unroll
        for (int r = 0; r < 4; ++r)
          sT[(row + r) * 128 + col] =
              f2bf(__expf(acc[mt][nt][r] * scale - mfin[nt]));
      }
    }
    __syncthreads();
#pragma unroll
    for (int c = 0; c < 8; ++c) {
      int flat = c * 2048 + tid * 8;
      int row = flat >> 7, col = flat & 127;
      *(bf16x8*)(Chi + (long)b * cBatch + (long)(m0 + row) * N + n0 + col) =
          *(const bf16x8*)(sT + flat);
    }
    return;
  }

  // MODE_PV: direct fp32 store.
#pragma unroll
  for (int nt = 0; nt < 4; ++nt) {
    int cn = n0 + wn * 64 + nt * 16 + ccol;
#pragma unroll
    for (int mt = 0; mt < 4; ++mt) {
#pragma unroll
      for (int r = 0; r < 4; ++r) {
        int cm_ = m0 + wm * 64 + mt * 16 + crow0 + r;
        Cf[(long)b * cBatch + (long)cm_ * N + cn] = acc[mt][nt][r] * scale;
      }
    }
  }
}

// ---------------------------------------------------------------------------
// Fold 16 q-tile partials -> ffac[b][t][k] = exp(M_t - M_k) / Z_k.
// Grid: B*S/256 = 32 blocks.
// ---------------------------------------------------------------------------
__global__ __launch_bounds__(256) void softmax_reduce(const float* __restrict__ Pmax,
                                                      const float* __restrict__ Psum,
                                                      float* __restrict__ Ffac) {
  int idx = blockIdx.x * 256 + threadIdx.x;   // b*2048 + k
  int b = idx >> 11, k = idx & (Sc - 1);
  const float* pm = Pmax + (long)b * 16 * Sc + k;
  const float* ps = Psum + (long)b * 16 * Sc + k;
  float M = -3.0e38f;
#pragma unroll
  for (int t = 0; t < 16; ++t) M = fmaxf(M, pm[(long)t * Sc]);
  float S = 0.f;
#pragma unroll
  for (int t = 0; t < 16; ++t)
    S += ps[(long)t * Sc] * __expf(pm[(long)t * Sc] - M);
  float inv = 1.0f / S;
  float* fo = Ffac + (long)b * 16 * Sc + k;
#pragma unroll
  for (int t = 0; t < 16; ++t)
    fo[(long)t * Sc] = __expf(pm[(long)t * Sc] - M) * inv;
}

// ---------------------------------------------------------------------------
extern "C" void kernel_launch(void* const* d_in, const int* in_sizes, int n_in,
                              void* d_out, int out_size, void* d_ws, size_t ws_size,
                              hipStream_t stream) {
  const float* x  = (const float*)d_in[0];
  const float* WQ = (const float*)d_in[1];
  const float* WK = (const float*)d_in[2];
  const float* WV = (const float*)d_in[3];
  float* out = (float*)d_out;
  char* ws = (char*)d_ws;
  const long MB = 1024L * 1024L;

  // Workspace layout (peak 131 MB).
  __bf16* xhi  = (__bf16*)(ws + 0 * MB);     // 16 MB
  __bf16* xlo  = (__bf16*)(ws + 16 * MB);    // 16 MB
  __bf16* wqhi = (__bf16*)(ws + 32 * MB);    // 2 MB each (element-wise split)
  __bf16* wqlo = (__bf16*)(ws + 34 * MB);
  __bf16* wkhi = (__bf16*)(ws + 36 * MB);
  __bf16* wklo = (__bf16*)(ws + 38 * MB);
  __bf16* wvthi= (__bf16*)(ws + 40 * MB);    // transposed (hi used by V GEMM)
  __bf16* wvtlo= (__bf16*)(ws + 42 * MB);
  __bf16* gthi = (__bf16*)(ws + 44 * MB);    // 2 MB each: Gt = (WQ WK^T)^T
  __bf16* gtlo = (__bf16*)(ws + 46 * MB);
  __bf16* thi  = (__bf16*)(ws + 48 * MB);    // 16 MB each: T = x*G
  __bf16* tlo  = (__bf16*)(ws + 64 * MB);
  __bf16* vt   = (__bf16*)(ws + 80 * MB);    // 16 MB, [B][DK][S]
  __bf16* P    = (__bf16*)(ws + 96 * MB);    // 32 MB, p = exp(s - M_t), bf16
  float*  pmax = (float*)(ws + 128 * MB);    // 512 KB, [B][16][S]
  float*  psum = (float*)(ws + 129 * MB);    // 512 KB
  float*  ffac = (float*)(ws + 130 * MB);    // 512 KB, [B][16][S]

  cast_all<<<40960, 256, 0, stream>>>(x, xhi, xlo, WQ, wqhi, wqlo, WK, wkhi, wklo);
  transpose_split<<<dim3(32, 32), dim3(32, 8), 0, stream>>>(WV, wvthi, wvtlo);

  // Gt[d][a] = G[a][d], G = WQ*WK^T: NT(A=WK, B=WQ) yields C[m][n]=G[n][m].
  gemm_tile<MODE_QK><<<dim3(DKc / 128, Dc / 128, 1), 256, 0, stream>>>(
      wkhi, wklo, wqhi, wqlo, nullptr, gthi, gtlo, nullptr, nullptr, nullptr, 1.0f);

  // T = x*G: NT(A=x, B=Gt).  [8192 x 1024]
  gemm_tile<MODE_QK><<<dim3(DKc / 128, BSc / 128, 1), 256, 0, stream>>>(
      xhi, xlo, gthi, gtlo, nullptr, thi, tlo, nullptr, nullptr, nullptr, 1.0f);

  // Vt = (x*WV)^T per batch.
  gemm_tile<MODE_V><<<dim3(DKc / 128, BSc / 128, 1), 256, 0, stream>>>(
      xhi, nullptr, wvthi, nullptr, nullptr, vt, nullptr, nullptr, nullptr, nullptr, 1.0f);

  // S = T*x^T * scale; emits p (bf16) + per-tile column max/expsum partials.
  gemm_tile<MODE_S><<<dim3(Sc / 128, Sc / 128, Bc), 256, 0, stream>>>(
      thi, tlo, xhi, xlo, nullptr, P, nullptr, pmax, psum, nullptr, 0.03125f);

  softmax_reduce<<<32, 256, 0, stream>>>(pmax, psum, ffac);

  // out = (p .* ffac) @ Vt^T — apply fused into A-staging.
  gemm_tile<MODE_PV><<<dim3(DKc / 128, Sc / 128, Bc), 256, 0, stream>>>(
      P, nullptr, vt, nullptr, out, nullptr, nullptr, nullptr, nullptr, ffac, 1.0f);
}

// Round 7
// 432.615 us; speedup vs baseline: 1.0950x; 1.0182x over previous
//
#include <hip/hip_runtime.h>

// Problem constants (fixed by the reference): B=4, S=2048, D=DK=1024.
constexpr int Bc  = 4;
constexpr int Sc  = 2048;
constexpr int Dc  = 1024;
constexpr int DKc = 1024;
constexpr long BSc = (long)Bc * Sc;      // 8192 flattened rows of x

typedef __attribute__((ext_vector_type(8))) __bf16 bf16x8;
typedef __attribute__((ext_vector_type(4))) float  floatx4;

__device__ inline __bf16 f2bf(float f) {
  unsigned u = __builtin_bit_cast(unsigned, f);
  u = (u + 0x7FFFu + ((u >> 16) & 1u)) >> 16;      // RNE
  unsigned short s = (unsigned short)u;
  return __builtin_bit_cast(__bf16, s);
}
__device__ inline float bf2f(__bf16 h) {
  unsigned u = ((unsigned)__builtin_bit_cast(unsigned short, h)) << 16;
  return __builtin_bit_cast(float, u);
}

// async global->LDS, 16B per lane. lds base must be wave-uniform; HW scatters
// lane i's 16B to ldsbase + i*16.
__device__ inline void stage16(const __bf16* g, __bf16* l) {
  __builtin_amdgcn_global_load_lds(
      (const __attribute__((address_space(1))) unsigned int*)g,
      (__attribute__((address_space(3))) unsigned int*)l, 16, 0, 0);
}

// ---------------------------------------------------------------------------
// prep: fp32->bf16 hi/lo splits for x (32768 blks), WQ (4096), WK (4096),
// plus WV transpose (hi only; 1024 blks). One dispatch (round-7).
// ---------------------------------------------------------------------------
__global__ __launch_bounds__(256) void prep(
    const float* __restrict__ x,  __bf16* __restrict__ xhi, __bf16* __restrict__ xlo,
    const float* __restrict__ wq, __bf16* __restrict__ qhi, __bf16* __restrict__ qlo,
    const float* __restrict__ wk, __bf16* __restrict__ khi, __bf16* __restrict__ klo,
    const float* __restrict__ wv, __bf16* __restrict__ vthi) {
  __shared__ float tile[32][33];
  long blk = blockIdx.x;
  if (blk >= 40960) {                 // WV transpose: Wt[dk][d] = W[d][dk]
    int t   = (int)(blk - 40960);
    int bx  = t & 31, by = t >> 5;
    int thx = threadIdx.x & 31, thy = threadIdx.x >> 5;   // 32 x 8
    int xI  = bx * 32 + thx, yI = by * 32 + thy;
#pragma unroll
    for (int j = 0; j < 32; j += 8)
      tile[thy + j][thx] = wv[(long)(yI + j) * DKc + xI];
    __syncthreads();
    int xO = by * 32 + thx, yO = bx * 32 + thy;
#pragma unroll
    for (int j = 0; j < 32; j += 8)
      vthi[(long)(yO + j) * Dc + xO] = f2bf(tile[thx][thy + j]);
    return;
  }
  const float* in; __bf16 *hi, *lo; long base;
  if (blk < 32768)      { in = x;  hi = xhi; lo = xlo; base = blk * 256; }
  else if (blk < 36864) { in = wq; hi = qhi; lo = qlo; base = (blk - 32768) * 256; }
  else                  { in = wk; hi = khi; lo = klo; base = (blk - 36864) * 256; }
  long i = base + threadIdx.x;
  float f = in[i];
  __bf16 h = f2bf(f);
  hi[i] = h;
  lo[i] = f2bf(f - bf2f(h));
}

// ---------------------------------------------------------------------------
// Shared m97-structure NT MFMA GEMM body. 128x128 tile, 4 waves 2x2, each
// 64x64 (4x4 accs of 16x16x32). BK=32 via global_load_lds width=16 with the
// XOR chunk swizzle on the global source (round-3: conflicts 8.4M -> 0).
// Caller allocates LDS and passes it in (wrappers size it per mode).
//
// MODE_QK: split (3 MFMA), bf16 hi+lo store via LDS round-trip.
// MODE_V : plain, TRANSPOSED store via LDS -> Vt[b][n][seq]
// MODE_S : split; epilogue computes per-column tile max M_t, stores
//          p = exp(s - M_t) bf16 + Pmax/Psum partials (round-6).
// MODE_PV: plain; A staged manually: attn = p * ffac[qtile][k] on the fly.
// ---------------------------------------------------------------------------
enum { MODE_QK = 0, MODE_V = 1, MODE_S = 2, MODE_PV = 3 };

template <int MODE>
__device__ __forceinline__ void gemm_body(
    char* smem,
    const __bf16* __restrict__ Ahi, const __bf16* __restrict__ Alo,
    const __bf16* __restrict__ Bhi, const __bf16* __restrict__ Blo,
    float* __restrict__ Cf, __bf16* __restrict__ Chi, __bf16* __restrict__ Clo,
    float* __restrict__ Pmax, float* __restrict__ Psum,
    const float* __restrict__ Ffac, float scale) {
  constexpr bool SPLIT = (MODE == MODE_QK || MODE == MODE_S);
  constexpr int  K = (MODE == MODE_PV) ? Sc : Dc;
  constexpr int  N = (MODE == MODE_S) ? Sc : DKc;
  constexpr long aBatch = (MODE == MODE_S) ? (long)Sc * DKc
                        : (MODE == MODE_PV) ? (long)Sc * Sc : 0;
  constexpr long bBatch = (MODE == MODE_S) ? (long)Sc * DKc
                        : (MODE == MODE_PV) ? (long)DKc * Sc : 0;
  constexpr long cBatch = (MODE == MODE_S) ? (long)Sc * Sc
                        : (MODE == MODE_PV) ? (long)Sc * DKc : 0;
  __bf16* sAh = (__bf16*)smem;           // [128][32] (chunk-swizzled)
  __bf16* sBh = sAh + 128 * 32;
  __bf16* sAl = sBh + 128 * 32;          // split only
  __bf16* sBl = sAl + 128 * 32;

  const int b    = blockIdx.z;
  const int wave = threadIdx.x >> 6;
  const int lane = threadIdx.x & 63;
  const int wm   = wave >> 1;            // 0..1
  const int wn   = wave & 1;             // 0..1
  const int m0   = blockIdx.y * 128;
  const int n0   = blockIdx.x * 128;

  const __bf16* Ab  = Ahi + (long)b * aBatch + (long)m0 * K;
  const __bf16* Bb  = Bhi + (long)b * bBatch + (long)n0 * K;
  const __bf16* Abl = SPLIT ? Alo + (long)b * aBatch + (long)m0 * K : nullptr;
  const __bf16* Bbl = SPLIT ? Blo + (long)b * bBatch + (long)n0 * K : nullptr;
  const float*  Fb  = (MODE == MODE_PV)
                    ? Ffac + ((long)b * 16 + blockIdx.y) * Sc : nullptr;

  // Async staging: wave w stages rows [w*32,w*32+32); lane (r,c) loads global
  // chunk c^((r>>1)&3) -> physical LDS slot base + lane*16B.
  const int sr   = lane >> 2;                       // 0..15
  const int sc_  = lane & 3;                        // 0..3
  const int scol = (sc_ ^ ((sr >> 1) & 3)) * 8;     // swizzled global col

  floatx4 acc[4][4];
  const floatx4 zero = {0.f, 0.f, 0.f, 0.f};
#pragma unroll
  for (int i = 0; i < 4; ++i)
#pragma unroll
    for (int j = 0; j < 4; ++j) acc[i][j] = zero;

  const int frow = lane & 15;
  // Fragment read: logical chunk = lane>>4; physical chunk is XOR'd by row.
  const int pko = ((lane >> 4) ^ ((frow >> 1) & 3)) * 8;

#pragma unroll 1
  for (int k0 = 0; k0 < K; k0 += 32) {
    if constexpr (MODE == MODE_PV) {
#pragma unroll
      for (int i = 0; i < 2; ++i) {
        const int rb = wave * 32 + i * 16;
        stage16(Bb + (long)(rb + sr) * K + k0 + scol, sBh + rb * 32);
      }
      // A manual: attn chunk = p * ffac, conflict-free lane-sequential write.
      const int tr = threadIdx.x >> 2;              // 0..63
      const int pc = threadIdx.x & 3;               // physical chunk
#pragma unroll
      for (int h = 0; h < 2; ++h) {
        int r  = h * 64 + tr;
        int lc = pc ^ ((r >> 1) & 3);               // logical chunk
        bf16x8 pv = *(const bf16x8*)(Ab + (long)r * K + k0 + lc * 8);
        const float* fp = Fb + k0 + lc * 8;
        bf16x8 o;
#pragma unroll
        for (int j = 0; j < 8; ++j) o[j] = f2bf(bf2f(pv[j]) * fp[j]);
        *(bf16x8*)(sAh + r * 32 + pc * 8) = o;
      }
    } else {
#pragma unroll
      for (int i = 0; i < 2; ++i) {
        const int rb = wave * 32 + i * 16;          // wave-uniform row base
        const long go = (long)(rb + sr) * K + k0 + scol;
        stage16(Ab + go, sAh + rb * 32);
        stage16(Bb + go, sBh + rb * 32);
        if constexpr (SPLIT) {
          stage16(Abl + go, sAl + rb * 32);
          stage16(Bbl + go, sBl + rb * 32);
        }
      }
    }
    __syncthreads();

    bf16x8 af[4], bfr[4], afl[4], bfl[4];
#pragma unroll
    for (int t = 0; t < 4; ++t) {
      af[t]  = *(const bf16x8*)(sAh + (wm * 64 + t * 16 + frow) * 32 + pko);
      bfr[t] = *(const bf16x8*)(sBh + (wn * 64 + t * 16 + frow) * 32 + pko);
      if constexpr (SPLIT) {
        afl[t] = *(const bf16x8*)(sAl + (wm * 64 + t * 16 + frow) * 32 + pko);
        bfl[t] = *(const bf16x8*)(sBl + (wn * 64 + t * 16 + frow) * 32 + pko);
      }
    }
#pragma unroll
    for (int mt = 0; mt < 4; ++mt)
#pragma unroll
      for (int nt = 0; nt < 4; ++nt) {
        acc[mt][nt] = __builtin_amdgcn_mfma_f32_16x16x32_bf16(af[mt], bfr[nt], acc[mt][nt], 0, 0, 0);
        if constexpr (SPLIT) {
          acc[mt][nt] = __builtin_amdgcn_mfma_f32_16x16x32_bf16(af[mt], bfl[nt], acc[mt][nt], 0, 0, 0);
          acc[mt][nt] = __builtin_amdgcn_mfma_f32_16x16x32_bf16(afl[mt], bfr[nt], acc[mt][nt], 0, 0, 0);
        }
      }
    __syncthreads();
  }

  // Epilogue. D layout: col=lane&15, row=(lane>>4)*4+reg (m89/m91-verified).
  const int crow0 = (lane >> 4) * 4;
  const int ccol  = lane & 15;
  const int tid   = threadIdx.x;

  if constexpr (MODE == MODE_QK) {
    __bf16* sT = (__bf16*)smem;          // [128][128] bf16 = 32KB
#pragma unroll 1
    for (int pass = 0; pass < 2; ++pass) {
      __syncthreads();
#pragma unroll
      for (int nt = 0; nt < 4; ++nt) {
        int col = wn * 64 + nt * 16 + ccol;
#pragma unroll
        for (int mt = 0; mt < 4; ++mt) {
          int row = wm * 64 + mt * 16 + crow0;
#pragma unroll
          for (int r = 0; r < 4; ++r) {
            float v = acc[mt][nt][r] * scale;
            __bf16 h = f2bf(v);
            sT[(row + r) * 128 + col] = pass ? f2bf(v - bf2f(h)) : h;
          }
        }
      }
      __syncthreads();
      __bf16* dst = pass ? Clo : Chi;
#pragma unroll
      for (int c = 0; c < 8; ++c) {
        int flat = c * 2048 + tid * 8;
        int row = flat >> 7, col = flat & 127;
        *(bf16x8*)(dst + (long)(m0 + row) * N + n0 + col) = *(const bf16x8*)(sT + flat);
      }
    }
    return;
  }

  if constexpr (MODE == MODE_V) {
    __bf16* sT = (__bf16*)smem;          // transpose via LDS
#pragma unroll
    for (int nt = 0; nt < 4; ++nt) {
      int nl = wn * 64 + nt * 16 + ccol;
#pragma unroll
      for (int mt = 0; mt < 4; ++mt) {
        int ml = wm * 64 + mt * 16 + crow0;
#pragma unroll
        for (int r = 0; r < 4; ++r)
          sT[(long)nl * 128 + ml + r] = f2bf(acc[mt][nt][r]);
      }
    }
    __syncthreads();
    const int bb   = m0 >> 11;          // tile fully within one batch
    const int seq0 = m0 & (Sc - 1);
    __bf16* dst = Chi + (long)bb * DKc * Sc + seq0;
#pragma unroll
    for (int c = 0; c < 8; ++c) {
      int flat = c * 2048 + tid * 8;    // elements; 16B per thread
      int row = flat >> 7, col = flat & 127;
      *(bf16x8*)(dst + (long)(n0 + row) * Sc + col) = *(const bf16x8*)(sT + flat);
    }
    return;
  }

  if constexpr (MODE == MODE_S) {
    // (1) per-column tile max over 128 rows.
    float cm[4];
#pragma unroll
    for (int nt = 0; nt < 4; ++nt) {
      float mx = -3.0e38f;
#pragma unroll
      for (int mt = 0; mt < 4; ++mt)
#pragma unroll
        for (int r = 0; r < 4; ++r) mx = fmaxf(mx, acc[mt][nt][r] * scale);
      cm[nt] = mx;
    }
#pragma unroll
    for (int off = 16; off <= 32; off <<= 1)
#pragma unroll
      for (int nt = 0; nt < 4; ++nt)
        cm[nt] = fmaxf(cm[nt], __shfl_xor(cm[nt], off, 64));
    float* smax = (float*)smem;          // [2][128]
    float* ssum = smax + 256;
    if (lane < 16)
#pragma unroll
      for (int nt = 0; nt < 4; ++nt)
        smax[wm * 128 + wn * 64 + nt * 16 + lane] = cm[nt];
    __syncthreads();
    float mfin[4];
#pragma unroll
    for (int nt = 0; nt < 4; ++nt) {
      int c = wn * 64 + nt * 16 + ccol;
      mfin[nt] = fmaxf(smax[c], smax[128 + c]);
    }
    // (2) column expsum vs tile max.
    float ps[4];
#pragma unroll
    for (int nt = 0; nt < 4; ++nt) {
      float s = 0.f;
#pragma unroll
      for (int mt = 0; mt < 4; ++mt)
#pragma unroll
        for (int r = 0; r < 4; ++r)
          s += __expf(acc[mt][nt][r] * scale - mfin[nt]);
      ps[nt] = s;
    }
#pragma unroll
    for (int off = 16; off <= 32; off <<= 1)
#pragma unroll
      for (int nt = 0; nt < 4; ++nt) ps[nt] += __shfl_xor(ps[nt], off, 64);
    if (lane < 16)
#pragma unroll
      for (int nt = 0; nt < 4; ++nt)
        ssum[wm * 128 + wn * 64 + nt * 16 + lane] = ps[nt];
    __syncthreads();
    if (tid < 128) {
      long o = ((long)b * 16 + blockIdx.y) * Sc + n0 + tid;
      Pmax[o] = fmaxf(smax[tid], smax[128 + tid]);
      Psum[o] = ssum[tid] + ssum[128 + tid];
    }
    __syncthreads();                     // smax/ssum dead; reuse as sT
    // (3) p = exp(s - M_t) -> bf16, LDS round-trip, coalesced store.
    __bf16* sT = (__bf16*)smem;
#pragma unroll
    for (int nt = 0; nt < 4; ++nt) {
      int col = wn * 64 + nt * 16 + ccol;
#pragma unroll
      for (int mt = 0; mt < 4; ++mt) {
        int row = wm * 64 + mt * 16 + crow0;
#pragma unroll
        for (int r = 0; r < 4; ++r)
          sT[(row + r) * 128 + col] =
              f2bf(__expf(acc[mt][nt][r] * scale - mfin[nt]));
      }
    }
    __syncthreads();
#pragma unroll
    for (int c = 0; c < 8; ++c) {
      int flat = c * 2048 + tid * 8;
      int row = flat >> 7, col = flat & 127;
      *(bf16x8*)(Chi + (long)b * cBatch + (long)(m0 + row) * N + n0 + col) =
          *(const bf16x8*)(sT + flat);
    }
    return;
  }

  // MODE_PV: direct fp32 store.
#pragma unroll
  for (int nt = 0; nt < 4; ++nt) {
    int cn = n0 + wn * 64 + nt * 16 + ccol;
#pragma unroll
    for (int mt = 0; mt < 4; ++mt) {
#pragma unroll
      for (int r = 0; r < 4; ++r) {
        int cm_ = m0 + wm * 64 + mt * 16 + crow0 + r;
        Cf[(long)b * cBatch + (long)cm_ * N + cn] = acc[mt][nt][r] * scale;
      }
    }
  }
}

// ---------------------------------------------------------------------------
// Wrappers (LDS sized per mode).
// gemm_tv: z=0 -> T = x*Gt^T (split); z=1 -> Vt = (x*WV)^T (plain). Fused
// dispatch merges two tails + one launch gap (round-7).
// ---------------------------------------------------------------------------
__global__ __launch_bounds__(256) void gemm_tv(
    const __bf16* __restrict__ xhi, const __bf16* __restrict__ xlo,
    const __bf16* __restrict__ gthi, const __bf16* __restrict__ gtlo,
    const __bf16* __restrict__ wvthi,
    __bf16* __restrict__ thi, __bf16* __restrict__ tlo, __bf16* __restrict__ vt) {
  __shared__ __align__(16) char smem[32768];
  if (blockIdx.z == 0)
    gemm_body<MODE_QK>(smem, xhi, xlo, gthi, gtlo, nullptr, thi, tlo,
                       nullptr, nullptr, nullptr, 1.0f);
  else
    gemm_body<MODE_V>(smem, xhi, nullptr, wvthi, nullptr, nullptr, vt, nullptr,
                      nullptr, nullptr, nullptr, 1.0f);
}

__global__ __launch_bounds__(256) void gemm_s(
    const __bf16* __restrict__ thi, const __bf16* __restrict__ tlo,
    const __bf16* __restrict__ xhi, const __bf16* __restrict__ xlo,
    __bf16* __restrict__ P, float* __restrict__ Pmax, float* __restrict__ Psum) {
  __shared__ __align__(16) char smem[32768];
  gemm_body<MODE_S>(smem, thi, tlo, xhi, xlo, nullptr, P, nullptr,
                    Pmax, Psum, nullptr, 0.03125f);
}

__global__ __launch_bounds__(256) void gemm_pv(
    const __bf16* __restrict__ P, const __bf16* __restrict__ vt,
    float* __restrict__ out, const float* __restrict__ ffac) {
  __shared__ __align__(16) char smem[16384];
  gemm_body<MODE_PV>(smem, P, nullptr, vt, nullptr, out, nullptr, nullptr,
                     nullptr, nullptr, ffac, 1.0f);
}

// ---------------------------------------------------------------------------
// G GEMM, 64x64 tiles (grid 16x16 = 256 blocks; the 128-tile version ran only
// 64 blocks on 256 CUs -> pure tail; round-7). Gt[m][n] = sum_k WK[m,k]WQ[n,k],
// split operands (3 MFMA), hi/lo output.
// ---------------------------------------------------------------------------
__global__ __launch_bounds__(256) void gemm_g64(
    const __bf16* __restrict__ Ahi, const __bf16* __restrict__ Alo,
    const __bf16* __restrict__ Bhi, const __bf16* __restrict__ Blo,
    __bf16* __restrict__ Chi, __bf16* __restrict__ Clo) {
  constexpr int K = Dc, N = DKc;
  __shared__ __align__(16) char smem[16384];
  __bf16* sAh = (__bf16*)smem;           // [64][32]
  __bf16* sBh = sAh + 64 * 32;
  __bf16* sAl = sBh + 64 * 32;
  __bf16* sBl = sAl + 64 * 32;

  const int wave = threadIdx.x >> 6;
  const int lane = threadIdx.x & 63;
  const int wm   = wave >> 1, wn = wave & 1;
  const int m0   = blockIdx.y * 64;
  const int n0   = blockIdx.x * 64;

  const int sr   = lane >> 2;
  const int sc_  = lane & 3;
  const int scol = (sc_ ^ ((sr >> 1) & 3)) * 8;
  const int frow = lane & 15;
  const int pko  = ((lane >> 4) ^ ((frow >> 1) & 3)) * 8;

  floatx4 acc[2][2];
  const floatx4 zero = {0.f, 0.f, 0.f, 0.f};
#pragma unroll
  for (int i = 0; i < 2; ++i)
#pragma unroll
    for (int j = 0; j < 2; ++j) acc[i][j] = zero;

#pragma unroll 1
  for (int k0 = 0; k0 < K; k0 += 32) {
    const int rb = wave * 16;                       // wave stages 16 rows
    const long ga = (long)(m0 + rb + sr) * K + k0 + scol;
    const long gb = (long)(n0 + rb + sr) * K + k0 + scol;
    stage16(Ahi + ga, sAh + rb * 32);
    stage16(Alo + ga, sAl + rb * 32);
    stage16(Bhi + gb, sBh + rb * 32);
    stage16(Blo + gb, sBl + rb * 32);
    __syncthreads();

    bf16x8 af[2], bfr[2], afl[2], bfl[2];
#pragma unroll
    for (int t = 0; t < 2; ++t) {
      af[t]  = *(const bf16x8*)(sAh + (wm * 32 + t * 16 + frow) * 32 + pko);
      bfr[t] = *(const bf16x8*)(sBh + (wn * 32 + t * 16 + frow) * 32 + pko);
      afl[t] = *(const bf16x8*)(sAl + (wm * 32 + t * 16 + frow) * 32 + pko);
      bfl[t] = *(const bf16x8*)(sBl + (wn * 32 + t * 16 + frow) * 32 + pko);
    }
#pragma unroll
    for (int mt = 0; mt < 2; ++mt)
#pragma unroll
      for (int nt = 0; nt < 2; ++nt) {
        acc[mt][nt] = __builtin_amdgcn_mfma_f32_16x16x32_bf16(af[mt], bfr[nt], acc[mt][nt], 0, 0, 0);
        acc[mt][nt] = __builtin_amdgcn_mfma_f32_16x16x32_bf16(af[mt], bfl[nt], acc[mt][nt], 0, 0, 0);
        acc[mt][nt] = __builtin_amdgcn_mfma_f32_16x16x32_bf16(afl[mt], bfr[nt], acc[mt][nt], 0, 0, 0);
      }
    __syncthreads();
  }

  const int crow0 = (lane >> 4) * 4;
  const int ccol  = lane & 15;
  const int tid   = threadIdx.x;
  __bf16* sT = (__bf16*)smem;            // [64][64] = 8KB
#pragma unroll 1
  for (int pass = 0; pass < 2; ++pass) {
    __syncthreads();
#pragma unroll
    for (int nt = 0; nt < 2; ++nt) {
      int col = wn * 32 + nt * 16 + ccol;
#pragma unroll
      for (int mt = 0; mt < 2; ++mt) {
        int row = wm * 32 + mt * 16 + crow0;
#pragma unroll
        for (int r = 0; r < 4; ++r) {
          float v = acc[mt][nt][r];
          __bf16 h = f2bf(v);
          sT[(row + r) * 64 + col] = pass ? f2bf(v - bf2f(h)) : h;
        }
      }
    }
    __syncthreads();
    __bf16* dst = pass ? Clo : Chi;
#pragma unroll
    for (int c = 0; c < 2; ++c) {
      int flat = c * 2048 + tid * 8;
      int row = flat >> 6, col = flat & 63;
      *(bf16x8*)(dst + (long)(m0 + row) * N + n0 + col) = *(const bf16x8*)(sT + flat);
    }
  }
}

// ---------------------------------------------------------------------------
// Fold 16 q-tile partials -> ffac[b][t][k] = exp(M_t - M_k) / Z_k.
// ---------------------------------------------------------------------------
__global__ __launch_bounds__(256) void softmax_reduce(const float* __restrict__ Pmax,
                                                      const float* __restrict__ Psum,
                                                      float* __restrict__ Ffac) {
  int idx = blockIdx.x * 256 + threadIdx.x;   // b*2048 + k
  int b = idx >> 11, k = idx & (Sc - 1);
  const float* pm = Pmax + (long)b * 16 * Sc + k;
  const float* ps = Psum + (long)b * 16 * Sc + k;
  float M = -3.0e38f;
#pragma unroll
  for (int t = 0; t < 16; ++t) M = fmaxf(M, pm[(long)t * Sc]);
  float S = 0.f;
#pragma unroll
  for (int t = 0; t < 16; ++t)
    S += ps[(long)t * Sc] * __expf(pm[(long)t * Sc] - M);
  float inv = 1.0f / S;
  float* fo = Ffac + (long)b * 16 * Sc + k;
#pragma unroll
  for (int t = 0; t < 16; ++t)
    fo[(long)t * Sc] = __expf(pm[(long)t * Sc] - M) * inv;
}

// ---------------------------------------------------------------------------
extern "C" void kernel_launch(void* const* d_in, const int* in_sizes, int n_in,
                              void* d_out, int out_size, void* d_ws, size_t ws_size,
                              hipStream_t stream) {
  const float* x  = (const float*)d_in[0];
  const float* WQ = (const float*)d_in[1];
  const float* WK = (const float*)d_in[2];
  const float* WV = (const float*)d_in[3];
  float* out = (float*)d_out;
  char* ws = (char*)d_ws;
  const long MB = 1024L * 1024L;

  // Workspace layout (peak ~130 MB).
  __bf16* xhi  = (__bf16*)(ws + 0 * MB);     // 16 MB
  __bf16* xlo  = (__bf16*)(ws + 16 * MB);    // 16 MB
  __bf16* wqhi = (__bf16*)(ws + 32 * MB);    // 2 MB each (element-wise split)
  __bf16* wqlo = (__bf16*)(ws + 34 * MB);
  __bf16* wkhi = (__bf16*)(ws + 36 * MB);
  __bf16* wklo = (__bf16*)(ws + 38 * MB);
  __bf16* wvthi= (__bf16*)(ws + 40 * MB);    // transposed, hi only
  __bf16* gthi = (__bf16*)(ws + 44 * MB);    // 2 MB each: Gt = (WQ WK^T)^T
  __bf16* gtlo = (__bf16*)(ws + 46 * MB);
  __bf16* thi  = (__bf16*)(ws + 48 * MB);    // 16 MB each: T = x*G
  __bf16* tlo  = (__bf16*)(ws + 64 * MB);
  __bf16* vt   = (__bf16*)(ws + 80 * MB);    // 16 MB, [B][DK][S]
  __bf16* P    = (__bf16*)(ws + 96 * MB);    // 32 MB, p = exp(s - M_t), bf16
  float*  pmax = (float*)(ws + 128 * MB);    // 512 KB, [B][16][S]
  float*  psum = (float*)(ws + 129 * MB);    // 512 KB
  float*  ffac = (float*)(ws + 130 * MB);    // 512 KB, [B][16][S]

  // 1. casts + WV transpose (one dispatch)
  prep<<<41984, 256, 0, stream>>>(x, xhi, xlo, WQ, wqhi, wqlo, WK, wkhi, wklo,
                                  WV, wvthi);

  // 2. Gt[d][a] = G[a][d]: NT(A=WK, B=WQ), 64x64 tiles -> 256 blocks.
  gemm_g64<<<dim3(16, 16), 256, 0, stream>>>(wkhi, wklo, wqhi, wqlo, gthi, gtlo);

  // 3. fused: z=0 T = x*G (split), z=1 Vt = (x*WV)^T (plain).
  gemm_tv<<<dim3(DKc / 128, BSc / 128, 2), 256, 0, stream>>>(
      xhi, xlo, gthi, gtlo, wvthi, thi, tlo, vt);

  // 4. S = T*x^T * scale; emits p (bf16) + per-tile column max/expsum.
  gemm_s<<<dim3(Sc / 128, Sc / 128, Bc), 256, 0, stream>>>(
      thi, tlo, xhi, xlo, P, pmax, psum);

  // 5. partials -> ffac
  softmax_reduce<<<32, 256, 0, stream>>>(pmax, psum, ffac);

  // 6. out = (p .* ffac) @ Vt^T — apply fused into A-staging.
  gemm_pv<<<dim3(DKc / 128, Sc / 128, Bc), 256, 0, stream>>>(P, vt, out, ffac);
}

// Round 8
// 423.465 us; speedup vs baseline: 1.1186x; 1.0216x over previous
//
#include <hip/hip_runtime.h>

// Problem constants (fixed by the reference): B=4, S=2048, D=DK=1024.
constexpr int Bc  = 4;
constexpr int Sc  = 2048;
constexpr int Dc  = 1024;
constexpr int DKc = 1024;
constexpr long BSc = (long)Bc * Sc;      // 8192 flattened rows of x

typedef __attribute__((ext_vector_type(8))) __bf16 bf16x8;
typedef __attribute__((ext_vector_type(4))) float  floatx4;

__device__ inline __bf16 f2bf(float f) {
  unsigned u = __builtin_bit_cast(unsigned, f);
  u = (u + 0x7FFFu + ((u >> 16) & 1u)) >> 16;      // RNE
  unsigned short s = (unsigned short)u;
  return __builtin_bit_cast(__bf16, s);
}
__device__ inline float bf2f(__bf16 h) {
  unsigned u = ((unsigned)__builtin_bit_cast(unsigned short, h)) << 16;
  return __builtin_bit_cast(float, u);
}

// async global->LDS, 16B per lane. lds base must be wave-uniform; HW scatters
// lane i's 16B to ldsbase + i*16.
__device__ inline void stage16(const __bf16* g, __bf16* l) {
  __builtin_amdgcn_global_load_lds(
      (const __attribute__((address_space(1))) unsigned int*)g,
      (__attribute__((address_space(3))) unsigned int*)l, 16, 0, 0);
}

// ---------------------------------------------------------------------------
// prep: fp32->bf16 hi/lo splits for x (32768 blks), WQ (4096), WK (4096),
// plus WV transpose (hi only; 1024 blks). One dispatch (round-7).
// ---------------------------------------------------------------------------
__global__ __launch_bounds__(256) void prep(
    const float* __restrict__ x,  __bf16* __restrict__ xhi, __bf16* __restrict__ xlo,
    const float* __restrict__ wq, __bf16* __restrict__ qhi, __bf16* __restrict__ qlo,
    const float* __restrict__ wk, __bf16* __restrict__ khi, __bf16* __restrict__ klo,
    const float* __restrict__ wv, __bf16* __restrict__ vthi) {
  __shared__ float tile[32][33];
  long blk = blockIdx.x;
  if (blk >= 40960) {                 // WV transpose: Wt[dk][d] = W[d][dk]
    int t   = (int)(blk - 40960);
    int bx  = t & 31, by = t >> 5;
    int thx = threadIdx.x & 31, thy = threadIdx.x >> 5;   // 32 x 8
    int xI  = bx * 32 + thx, yI = by * 32 + thy;
#pragma unroll
    for (int j = 0; j < 32; j += 8)
      tile[thy + j][thx] = wv[(long)(yI + j) * DKc + xI];
    __syncthreads();
    int xO = by * 32 + thx, yO = bx * 32 + thy;
#pragma unroll
    for (int j = 0; j < 32; j += 8)
      vthi[(long)(yO + j) * Dc + xO] = f2bf(tile[thx][thy + j]);
    return;
  }
  const float* in; __bf16 *hi, *lo; long base;
  if (blk < 32768)      { in = x;  hi = xhi; lo = xlo; base = blk * 256; }
  else if (blk < 36864) { in = wq; hi = qhi; lo = qlo; base = (blk - 32768) * 256; }
  else                  { in = wk; hi = khi; lo = klo; base = (blk - 36864) * 256; }
  long i = base + threadIdx.x;
  float f = in[i];
  __bf16 h = f2bf(f);
  hi[i] = h;
  lo[i] = f2bf(f - bf2f(h));
}

// ---------------------------------------------------------------------------
// Shared m97-structure NT MFMA GEMM body. 128x128 tile, 4 waves 2x2, each
// 64x64 (4x4 accs of 16x16x32). BK=32 via global_load_lds width=16 with the
// XOR chunk swizzle on the global source (round-3: conflicts 8.4M -> 0).
// One kernel per mode (round-8: fusing T+V merged register budgets, VGPR 152,
// occupancy 11% -> unfused).
//
// MODE_QK: split (3 MFMA), bf16 hi+lo store via LDS round-trip.
// MODE_V : plain, TRANSPOSED store via padded LDS (stride 136: 16-way -> 2-way
//          bank aliasing on the column writes; round-8).
// MODE_S : split; epilogue computes per-column tile max M_t, stores
//          p = exp(s - M_t) bf16 + Pmax/Psum partials (round-6).
// MODE_PV: plain; A staged manually: attn = p * ffac[qtile][k] on the fly.
// ---------------------------------------------------------------------------
enum { MODE_QK = 0, MODE_V = 1, MODE_S = 2, MODE_PV = 3 };
constexpr int VSTR = 136;   // padded stride for the V transpose epilogue

template <int MODE>
__device__ __forceinline__ void gemm_body(
    char* smem,
    const __bf16* __restrict__ Ahi, const __bf16* __restrict__ Alo,
    const __bf16* __restrict__ Bhi, const __bf16* __restrict__ Blo,
    float* __restrict__ Cf, __bf16* __restrict__ Chi, __bf16* __restrict__ Clo,
    float* __restrict__ Pmax, float* __restrict__ Psum,
    const float* __restrict__ Ffac, float scale) {
  constexpr bool SPLIT = (MODE == MODE_QK || MODE == MODE_S);
  constexpr int  K = (MODE == MODE_PV) ? Sc : Dc;
  constexpr int  N = (MODE == MODE_S) ? Sc : DKc;
  constexpr long aBatch = (MODE == MODE_S) ? (long)Sc * DKc
                        : (MODE == MODE_PV) ? (long)Sc * Sc : 0;
  constexpr long bBatch = (MODE == MODE_S) ? (long)Sc * DKc
                        : (MODE == MODE_PV) ? (long)DKc * Sc : 0;
  constexpr long cBatch = (MODE == MODE_S) ? (long)Sc * Sc
                        : (MODE == MODE_PV) ? (long)Sc * DKc : 0;
  __bf16* sAh = (__bf16*)smem;           // [128][32] (chunk-swizzled)
  __bf16* sBh = sAh + 128 * 32;
  __bf16* sAl = sBh + 128 * 32;          // split only
  __bf16* sBl = sAl + 128 * 32;

  const int b    = blockIdx.z;
  const int wave = threadIdx.x >> 6;
  const int lane = threadIdx.x & 63;
  const int wm   = wave >> 1;            // 0..1
  const int wn   = wave & 1;             // 0..1
  const int m0   = blockIdx.y * 128;
  const int n0   = blockIdx.x * 128;

  const __bf16* Ab  = Ahi + (long)b * aBatch + (long)m0 * K;
  const __bf16* Bb  = Bhi + (long)b * bBatch + (long)n0 * K;
  const __bf16* Abl = SPLIT ? Alo + (long)b * aBatch + (long)m0 * K : nullptr;
  const __bf16* Bbl = SPLIT ? Blo + (long)b * bBatch + (long)n0 * K : nullptr;
  const float*  Fb  = (MODE == MODE_PV)
                    ? Ffac + ((long)b * 16 + blockIdx.y) * Sc : nullptr;

  // Async staging: wave w stages rows [w*32,w*32+32); lane (r,c) loads global
  // chunk c^((r>>1)&3) -> physical LDS slot base + lane*16B.
  const int sr   = lane >> 2;                       // 0..15
  const int sc_  = lane & 3;                        // 0..3
  const int scol = (sc_ ^ ((sr >> 1) & 3)) * 8;     // swizzled global col

  floatx4 acc[4][4];
  const floatx4 zero = {0.f, 0.f, 0.f, 0.f};
#pragma unroll
  for (int i = 0; i < 4; ++i)
#pragma unroll
    for (int j = 0; j < 4; ++j) acc[i][j] = zero;

  const int frow = lane & 15;
  // Fragment read: logical chunk = lane>>4; physical chunk is XOR'd by row.
  const int pko = ((lane >> 4) ^ ((frow >> 1) & 3)) * 8;

#pragma unroll 1
  for (int k0 = 0; k0 < K; k0 += 32) {
    if constexpr (MODE == MODE_PV) {
#pragma unroll
      for (int i = 0; i < 2; ++i) {
        const int rb = wave * 32 + i * 16;
        stage16(Bb + (long)(rb + sr) * K + k0 + scol, sBh + rb * 32);
      }
      // A manual: attn chunk = p * ffac, conflict-free lane-sequential write.
      const int tr = threadIdx.x >> 2;              // 0..63
      const int pc = threadIdx.x & 3;               // physical chunk
#pragma unroll
      for (int h = 0; h < 2; ++h) {
        int r  = h * 64 + tr;
        int lc = pc ^ ((r >> 1) & 3);               // logical chunk
        bf16x8 pv = *(const bf16x8*)(Ab + (long)r * K + k0 + lc * 8);
        const float* fp = Fb + k0 + lc * 8;
        bf16x8 o;
#pragma unroll
        for (int j = 0; j < 8; ++j) o[j] = f2bf(bf2f(pv[j]) * fp[j]);
        *(bf16x8*)(sAh + r * 32 + pc * 8) = o;
      }
    } else {
#pragma unroll
      for (int i = 0; i < 2; ++i) {
        const int rb = wave * 32 + i * 16;          // wave-uniform row base
        const long go = (long)(rb + sr) * K + k0 + scol;
        stage16(Ab + go, sAh + rb * 32);
        stage16(Bb + go, sBh + rb * 32);
        if constexpr (SPLIT) {
          stage16(Abl + go, sAl + rb * 32);
          stage16(Bbl + go, sBl + rb * 32);
        }
      }
    }
    __syncthreads();

    bf16x8 af[4], bfr[4], afl[4], bfl[4];
#pragma unroll
    for (int t = 0; t < 4; ++t) {
      af[t]  = *(const bf16x8*)(sAh + (wm * 64 + t * 16 + frow) * 32 + pko);
      bfr[t] = *(const bf16x8*)(sBh + (wn * 64 + t * 16 + frow) * 32 + pko);
      if constexpr (SPLIT) {
        afl[t] = *(const bf16x8*)(sAl + (wm * 64 + t * 16 + frow) * 32 + pko);
        bfl[t] = *(const bf16x8*)(sBl + (wn * 64 + t * 16 + frow) * 32 + pko);
      }
    }
#pragma unroll
    for (int mt = 0; mt < 4; ++mt)
#pragma unroll
      for (int nt = 0; nt < 4; ++nt) {
        acc[mt][nt] = __builtin_amdgcn_mfma_f32_16x16x32_bf16(af[mt], bfr[nt], acc[mt][nt], 0, 0, 0);
        if constexpr (SPLIT) {
          acc[mt][nt] = __builtin_amdgcn_mfma_f32_16x16x32_bf16(af[mt], bfl[nt], acc[mt][nt], 0, 0, 0);
          acc[mt][nt] = __builtin_amdgcn_mfma_f32_16x16x32_bf16(afl[mt], bfr[nt], acc[mt][nt], 0, 0, 0);
        }
      }
    __syncthreads();
  }

  // Epilogue. D layout: col=lane&15, row=(lane>>4)*4+reg (m89/m91-verified).
  const int crow0 = (lane >> 4) * 4;
  const int ccol  = lane & 15;
  const int tid   = threadIdx.x;

  if constexpr (MODE == MODE_QK) {
    __bf16* sT = (__bf16*)smem;          // [128][128] bf16 = 32KB
#pragma unroll 1
    for (int pass = 0; pass < 2; ++pass) {
      __syncthreads();
#pragma unroll
      for (int nt = 0; nt < 4; ++nt) {
        int col = wn * 64 + nt * 16 + ccol;
#pragma unroll
        for (int mt = 0; mt < 4; ++mt) {
          int row = wm * 64 + mt * 16 + crow0;
#pragma unroll
          for (int r = 0; r < 4; ++r) {
            float v = acc[mt][nt][r] * scale;
            __bf16 h = f2bf(v);
            sT[(row + r) * 128 + col] = pass ? f2bf(v - bf2f(h)) : h;
          }
        }
      }
      __syncthreads();
      __bf16* dst = pass ? Clo : Chi;
#pragma unroll
      for (int c = 0; c < 8; ++c) {
        int flat = c * 2048 + tid * 8;
        int row = flat >> 7, col = flat & 127;
        *(bf16x8*)(dst + (long)(m0 + row) * N + n0 + col) = *(const bf16x8*)(sT + flat);
      }
    }
    return;
  }

  if constexpr (MODE == MODE_V) {
    // Transpose via LDS, padded stride VSTR=136 (272B = 17x16B: rows stay
    // 16B-aligned; bank advance 4/row -> 2-way aliasing, free per m136).
    __bf16* sT = (__bf16*)smem;          // [128][VSTR]
#pragma unroll
    for (int nt = 0; nt < 4; ++nt) {
      int nl = wn * 64 + nt * 16 + ccol;
#pragma unroll
      for (int mt = 0; mt < 4; ++mt) {
        int ml = wm * 64 + mt * 16 + crow0;
#pragma unroll
        for (int r = 0; r < 4; ++r)
          sT[(long)nl * VSTR + ml + r] = f2bf(acc[mt][nt][r]);
      }
    }
    __syncthreads();
    const int bb   = m0 >> 11;          // tile fully within one batch
    const int seq0 = m0 & (Sc - 1);
    __bf16* dst = Chi + (long)bb * DKc * Sc + seq0;
#pragma unroll
    for (int c = 0; c < 8; ++c) {
      int flat = c * 2048 + tid * 8;    // logical 128x128; 16B per thread
      int row = flat >> 7, col = flat & 127;
      *(bf16x8*)(dst + (long)(n0 + row) * Sc + col) =
          *(const bf16x8*)(sT + (long)row * VSTR + col);
    }
    return;
  }

  if constexpr (MODE == MODE_S) {
    // (1) per-column tile max over 128 rows.
    float cm[4];
#pragma unroll
    for (int nt = 0; nt < 4; ++nt) {
      float mx = -3.0e38f;
#pragma unroll
      for (int mt = 0; mt < 4; ++mt)
#pragma unroll
        for (int r = 0; r < 4; ++r) mx = fmaxf(mx, acc[mt][nt][r] * scale);
      cm[nt] = mx;
    }
#pragma unroll
    for (int off = 16; off <= 32; off <<= 1)
#pragma unroll
      for (int nt = 0; nt < 4; ++nt)
        cm[nt] = fmaxf(cm[nt], __shfl_xor(cm[nt], off, 64));
    float* smax = (float*)smem;          // [2][128]
    float* ssum = smax + 256;
    if (lane < 16)
#pragma unroll
      for (int nt = 0; nt < 4; ++nt)
        smax[wm * 128 + wn * 64 + nt * 16 + lane] = cm[nt];
    __syncthreads();
    float mfin[4];
#pragma unroll
    for (int nt = 0; nt < 4; ++nt) {
      int c = wn * 64 + nt * 16 + ccol;
      mfin[nt] = fmaxf(smax[c], smax[128 + c]);
    }
    // (2) column expsum vs tile max.
    float ps[4];
#pragma unroll
    for (int nt = 0; nt < 4; ++nt) {
      float s = 0.f;
#pragma unroll
      for (int mt = 0; mt < 4; ++mt)
#pragma unroll
        for (int r = 0; r < 4; ++r)
          s += __expf(acc[mt][nt][r] * scale - mfin[nt]);
      ps[nt] = s;
    }
#pragma unroll
    for (int off = 16; off <= 32; off <<= 1)
#pragma unroll
      for (int nt = 0; nt < 4; ++nt) ps[nt] += __shfl_xor(ps[nt], off, 64);
    if (lane < 16)
#pragma unroll
      for (int nt = 0; nt < 4; ++nt)
        ssum[wm * 128 + wn * 64 + nt * 16 + lane] = ps[nt];
    __syncthreads();
    if (tid < 128) {
      long o = ((long)b * 16 + blockIdx.y) * Sc + n0 + tid;
      Pmax[o] = fmaxf(smax[tid], smax[128 + tid]);
      Psum[o] = ssum[tid] + ssum[128 + tid];
    }
    __syncthreads();                     // smax/ssum dead; reuse as sT
    // (3) p = exp(s - M_t) -> bf16, LDS round-trip, coalesced store.
    __bf16* sT = (__bf16*)smem;
#pragma unroll
    for (int nt = 0; nt < 4; ++nt) {
      int col = wn * 64 + nt * 16 + ccol;
#pragma unroll
      for (int mt = 0; mt < 4; ++mt) {
        int row = wm * 64 + mt * 16 + crow0;
#pragma unroll
        for (int r = 0; r < 4; ++r)
          sT[(row + r) * 128 + col] =
              f2bf(__expf(acc[mt][nt][r] * scale - mfin[nt]));
      }
    }
    __syncthreads();
#pragma unroll
    for (int c = 0; c < 8; ++c) {
      int flat = c * 2048 + tid * 8;
      int row = flat >> 7, col = flat & 127;
      *(bf16x8*)(Chi + (long)b * cBatch + (long)(m0 + row) * N + n0 + col) =
          *(const bf16x8*)(sT + flat);
    }
    return;
  }

  // MODE_PV: direct fp32 store.
#pragma unroll
  for (int nt = 0; nt < 4; ++nt) {
    int cn = n0 + wn * 64 + nt * 16 + ccol;
#pragma unroll
    for (int mt = 0; mt < 4; ++mt) {
#pragma unroll
      for (int r = 0; r < 4; ++r) {
        int cm_ = m0 + wm * 64 + mt * 16 + crow0 + r;
        Cf[(long)b * cBatch + (long)cm_ * N + cn] = acc[mt][nt][r] * scale;
      }
    }
  }
}

// ---------------------------------------------------------------------------
// Wrappers — one kernel per mode (separate register budgets).
// ---------------------------------------------------------------------------
__global__ __launch_bounds__(256) void gemm_t(
    const __bf16* __restrict__ xhi, const __bf16* __restrict__ xlo,
    const __bf16* __restrict__ gthi, const __bf16* __restrict__ gtlo,
    __bf16* __restrict__ thi, __bf16* __restrict__ tlo) {
  __shared__ __align__(16) char smem[32768];
  gemm_body<MODE_QK>(smem, xhi, xlo, gthi, gtlo, nullptr, thi, tlo,
                     nullptr, nullptr, nullptr, 1.0f);
}

__global__ __launch_bounds__(256) void gemm_v(
    const __bf16* __restrict__ xhi, const __bf16* __restrict__ wvthi,
    __bf16* __restrict__ vt) {
  __shared__ __align__(16) char smem[128 * VSTR * 2];   // 34 KB (epilogue)
  gemm_body<MODE_V>(smem, xhi, nullptr, wvthi, nullptr, nullptr, vt, nullptr,
                    nullptr, nullptr, nullptr, 1.0f);
}

__global__ __launch_bounds__(256) void gemm_s(
    const __bf16* __restrict__ thi, const __bf16* __restrict__ tlo,
    const __bf16* __restrict__ xhi, const __bf16* __restrict__ xlo,
    __bf16* __restrict__ P, float* __restrict__ Pmax, float* __restrict__ Psum) {
  __shared__ __align__(16) char smem[32768];
  gemm_body<MODE_S>(smem, thi, tlo, xhi, xlo, nullptr, P, nullptr,
                    Pmax, Psum, nullptr, 0.03125f);
}

__global__ __launch_bounds__(256) void gemm_pv(
    const __bf16* __restrict__ P, const __bf16* __restrict__ vt,
    float* __restrict__ out, const float* __restrict__ ffac) {
  __shared__ __align__(16) char smem[16384];
  gemm_body<MODE_PV>(smem, P, nullptr, vt, nullptr, out, nullptr, nullptr,
                     nullptr, nullptr, ffac, 1.0f);
}

// ---------------------------------------------------------------------------
// G GEMM, 64x64 tiles (256 blocks; round-7). Gt[m][n] = sum_k WK[m,k]WQ[n,k],
// split operands (3 MFMA), hi/lo output.
// ---------------------------------------------------------------------------
__global__ __launch_bounds__(256) void gemm_g64(
    const __bf16* __restrict__ Ahi, const __bf16* __restrict__ Alo,
    const __bf16* __restrict__ Bhi, const __bf16* __restrict__ Blo,
    __bf16* __restrict__ Chi, __bf16* __restrict__ Clo) {
  constexpr int K = Dc, N = DKc;
  __shared__ __align__(16) char smem[16384];
  __bf16* sAh = (__bf16*)smem;           // [64][32]
  __bf16* sBh = sAh + 64 * 32;
  __bf16* sAl = sBh + 64 * 32;
  __bf16* sBl = sAl + 64 * 32;

  const int wave = threadIdx.x >> 6;
  const int lane = threadIdx.x & 63;
  const int wm   = wave >> 1, wn = wave & 1;
  const int m0   = blockIdx.y * 64;
  const int n0   = blockIdx.x * 64;

  const int sr   = lane >> 2;
  const int sc_  = lane & 3;
  const int scol = (sc_ ^ ((sr >> 1) & 3)) * 8;
  const int frow = lane & 15;
  const int pko  = ((lane >> 4) ^ ((frow >> 1) & 3)) * 8;

  floatx4 acc[2][2];
  const floatx4 zero = {0.f, 0.f, 0.f, 0.f};
#pragma unroll
  for (int i = 0; i < 2; ++i)
#pragma unroll
    for (int j = 0; j < 2; ++j) acc[i][j] = zero;

#pragma unroll 1
  for (int k0 = 0; k0 < K; k0 += 32) {
    const int rb = wave * 16;                       // wave stages 16 rows
    const long ga = (long)(m0 + rb + sr) * K + k0 + scol;
    const long gb = (long)(n0 + rb + sr) * K + k0 + scol;
    stage16(Ahi + ga, sAh + rb * 32);
    stage16(Alo + ga, sAl + rb * 32);
    stage16(Bhi + gb, sBh + rb * 32);
    stage16(Blo + gb, sBl + rb * 32);
    __syncthreads();

    bf16x8 af[2], bfr[2], afl[2], bfl[2];
#pragma unroll
    for (int t = 0; t < 2; ++t) {
      af[t]  = *(const bf16x8*)(sAh + (wm * 32 + t * 16 + frow) * 32 + pko);
      bfr[t] = *(const bf16x8*)(sBh + (wn * 32 + t * 16 + frow) * 32 + pko);
      afl[t] = *(const bf16x8*)(sAl + (wm * 32 + t * 16 + frow) * 32 + pko);
      bfl[t] = *(const bf16x8*)(sBl + (wn * 32 + t * 16 + frow) * 32 + pko);
    }
#pragma unroll
    for (int mt = 0; mt < 2; ++mt)
#pragma unroll
      for (int nt = 0; nt < 2; ++nt) {
        acc[mt][nt] = __builtin_amdgcn_mfma_f32_16x16x32_bf16(af[mt], bfr[nt], acc[mt][nt], 0, 0, 0);
        acc[mt][nt] = __builtin_amdgcn_mfma_f32_16x16x32_bf16(af[mt], bfl[nt], acc[mt][nt], 0, 0, 0);
        acc[mt][nt] = __builtin_amdgcn_mfma_f32_16x16x32_bf16(afl[mt], bfr[nt], acc[mt][nt], 0, 0, 0);
      }
    __syncthreads();
  }

  const int crow0 = (lane >> 4) * 4;
  const int ccol  = lane & 15;
  const int tid   = threadIdx.x;
  __bf16* sT = (__bf16*)smem;            // [64][64] = 8KB
#pragma unroll 1
  for (int pass = 0; pass < 2; ++pass) {
    __syncthreads();
#pragma unroll
    for (int nt = 0; nt < 2; ++nt) {
      int col = wn * 32 + nt * 16 + ccol;
#pragma unroll
      for (int mt = 0; mt < 2; ++mt) {
        int row = wm * 32 + mt * 16 + crow0;
#pragma unroll
        for (int r = 0; r < 4; ++r) {
          float v = acc[mt][nt][r];
          __bf16 h = f2bf(v);
          sT[(row + r) * 64 + col] = pass ? f2bf(v - bf2f(h)) : h;
        }
      }
    }
    __syncthreads();
    __bf16* dst = pass ? Clo : Chi;
#pragma unroll
    for (int c = 0; c < 2; ++c) {
      int flat = c * 2048 + tid * 8;
      int row = flat >> 6, col = flat & 63;
      *(bf16x8*)(dst + (long)(m0 + row) * N + n0 + col) = *(const bf16x8*)(sT + flat);
    }
  }
}

// ---------------------------------------------------------------------------
// Fold 16 q-tile partials -> ffac[b][t][k] = exp(M_t - M_k) / Z_k.
// ---------------------------------------------------------------------------
__global__ __launch_bounds__(256) void softmax_reduce(const float* __restrict__ Pmax,
                                                      const float* __restrict__ Psum,
                                                      float* __restrict__ Ffac) {
  int idx = blockIdx.x * 256 + threadIdx.x;   // b*2048 + k
  int b = idx >> 11, k = idx & (Sc - 1);
  const float* pm = Pmax + (long)b * 16 * Sc + k;
  const float* ps = Psum + (long)b * 16 * Sc + k;
  float M = -3.0e38f;
#pragma unroll
  for (int t = 0; t < 16; ++t) M = fmaxf(M, pm[(long)t * Sc]);
  float S = 0.f;
#pragma unroll
  for (int t = 0; t < 16; ++t)
    S += ps[(long)t * Sc] * __expf(pm[(long)t * Sc] - M);
  float inv = 1.0f / S;
  float* fo = Ffac + (long)b * 16 * Sc + k;
#pragma unroll
  for (int t = 0; t < 16; ++t)
    fo[(long)t * Sc] = __expf(pm[(long)t * Sc] - M) * inv;
}

// ---------------------------------------------------------------------------
extern "C" void kernel_launch(void* const* d_in, const int* in_sizes, int n_in,
                              void* d_out, int out_size, void* d_ws, size_t ws_size,
                              hipStream_t stream) {
  const float* x  = (const float*)d_in[0];
  const float* WQ = (const float*)d_in[1];
  const float* WK = (const float*)d_in[2];
  const float* WV = (const float*)d_in[3];
  float* out = (float*)d_out;
  char* ws = (char*)d_ws;
  const long MB = 1024L * 1024L;

  // Workspace layout (peak ~130 MB).
  __bf16* xhi  = (__bf16*)(ws + 0 * MB);     // 16 MB
  __bf16* xlo  = (__bf16*)(ws + 16 * MB);    // 16 MB
  __bf16* wqhi = (__bf16*)(ws + 32 * MB);    // 2 MB each (element-wise split)
  __bf16* wqlo = (__bf16*)(ws + 34 * MB);
  __bf16* wkhi = (__bf16*)(ws + 36 * MB);
  __bf16* wklo = (__bf16*)(ws + 38 * MB);
  __bf16* wvthi= (__bf16*)(ws + 40 * MB);    // transposed, hi only
  __bf16* gthi = (__bf16*)(ws + 44 * MB);    // 2 MB each: Gt = (WQ WK^T)^T
  __bf16* gtlo = (__bf16*)(ws + 46 * MB);
  __bf16* thi  = (__bf16*)(ws + 48 * MB);    // 16 MB each: T = x*G
  __bf16* tlo  = (__bf16*)(ws + 64 * MB);
  __bf16* vt   = (__bf16*)(ws + 80 * MB);    // 16 MB, [B][DK][S]
  __bf16* P    = (__bf16*)(ws + 96 * MB);    // 32 MB, p = exp(s - M_t), bf16
  float*  pmax = (float*)(ws + 128 * MB);    // 512 KB, [B][16][S]
  float*  psum = (float*)(ws + 129 * MB);    // 512 KB
  float*  ffac = (float*)(ws + 130 * MB);    // 512 KB, [B][16][S]

  // 1. casts + WV transpose (one dispatch)
  prep<<<41984, 256, 0, stream>>>(x, xhi, xlo, WQ, wqhi, wqlo, WK, wkhi, wklo,
                                  WV, wvthi);

  // 2. Gt[d][a] = G[a][d]: NT(A=WK, B=WQ), 64x64 tiles -> 256 blocks.
  gemm_g64<<<dim3(16, 16), 256, 0, stream>>>(wkhi, wklo, wqhi, wqlo, gthi, gtlo);

  // 3. T = x*G (split).
  gemm_t<<<dim3(DKc / 128, BSc / 128, 1), 256, 0, stream>>>(
      xhi, xlo, gthi, gtlo, thi, tlo);

  // 4. Vt = (x*WV)^T per batch (plain).
  gemm_v<<<dim3(DKc / 128, BSc / 128, 1), 256, 0, stream>>>(xhi, wvthi, vt);

  // 5. S = T*x^T * scale; emits p (bf16) + per-tile column max/expsum.
  gemm_s<<<dim3(Sc / 128, Sc / 128, Bc), 256, 0, stream>>>(
      thi, tlo, xhi, xlo, P, pmax, psum);

  // 6. partials -> ffac
  softmax_reduce<<<32, 256, 0, stream>>>(pmax, psum, ffac);

  // 7. out = (p .* ffac) @ Vt^T — apply fused into A-staging.
  gemm_pv<<<dim3(DKc / 128, Sc / 128, Bc), 256, 0, stream>>>(P, vt, out, ffac);
}